// Round 1
// baseline (9191.272 us; speedup 1.0000x reference)
//
#include <hip/hip_runtime.h>

#define NN 4096
#define DM 1024
#define MD 8
#define NCLS 64
#define NB 128          // B-items (8-col slices) per level
#define TC 8            // cols per B-item
#define GBLK 512        // persistent dataflow blocks
#define MAXL 4097

// meta layout (int offsets within meta region of d_ws)
#define MI_NLEV 0
#define MI_TOTAL 1
#define MI_TICKET 2
#define MI_LO 16        // levelOffset[nL+1]
#define MI_POS 8192     // pos[4096]  (node -> permuted row)
#define MI_PERM 12288   // perm[4096] (row -> node)
#define MI_HDONE 16384  // per-level h-done counters
#define MI_GDONE 20480  // per-level g-done counters

__device__ __forceinline__ float gelu_f(float x) {
  return 0.5f * x * (1.0f + erff(x * 0.70710678118654752440f));
}

// ---------------- prologue: levels + counting sort + flag reset ----------------
__global__ __launch_bounds__(1024) void k_prologue(
    const int* __restrict__ dep_idx, const int* __restrict__ dep_mask,
    int* __restrict__ meta) {
  __shared__ int lvl[NN];
  __shared__ int cnt[NN];
  __shared__ int s_changed, s_max;
  const int t = threadIdx.x;
  for (int i = t; i < NN; i += 1024) { lvl[i] = 0; cnt[i] = 0; }
  if (t == 0) s_max = 0;
  __syncthreads();
  // Gauss-Seidel-ish sweeps; monotone, converges to longest-path levels.
  for (int it = 0; it < NN; ++it) {
    if (t == 0) s_changed = 0;
    __syncthreads();
    #pragma unroll
    for (int u = 0; u < 4; ++u) {
      const int i = t * 4 + u;
      int m = 0;
      #pragma unroll
      for (int d = 0; d < MD; ++d) {
        if (dep_mask[i * MD + d]) {
          int l = lvl[dep_idx[i * MD + d]] + 1;
          m = m > l ? m : l;
        }
      }
      if (m > lvl[i]) { lvl[i] = m; s_changed = 1; }
    }
    __syncthreads();
    if (!s_changed) break;
  }
  for (int i = t; i < NN; i += 1024) { atomicAdd(&cnt[lvl[i]], 1); atomicMax(&s_max, lvl[i]); }
  __syncthreads();
  const int nL = s_max + 1;
  if (t == 0) {
    int off = 0;
    for (int l = 0; l < nL; ++l) { int c = cnt[l]; meta[MI_LO + l] = off; cnt[l] = off; off += c; }
    meta[MI_LO + nL] = off;
    meta[MI_NLEV] = nL;
    meta[MI_TOTAL] = NN + nL * NB;
    meta[MI_TICKET] = 0;
  }
  __syncthreads();
  for (int i = t; i < NN; i += 1024) {
    int r = atomicAdd(&cnt[lvl[i]], 1);
    meta[MI_POS + i] = r;
    meta[MI_PERM + r] = i;
  }
  for (int i = t; i < NN; i += 1024) { meta[MI_HDONE + i] = 0; meta[MI_GDONE + i] = 0; }
}

// ---------------- preQ = Q @ W1[:, :1024]^T + b1  (fp32 tiled GEMM) ----------------
__global__ __launch_bounds__(256) void k_preq(
    const float* __restrict__ Q, const float* __restrict__ W1,
    const float* __restrict__ b1, float* __restrict__ preQ) {
  __shared__ float As[16][65];
  __shared__ float Bs[16][65];
  const int t = threadIdx.x;
  const int m0 = blockIdx.y * 64, n0 = blockIdx.x * 64;
  const int lm = t >> 2;
  const int lk = (t & 3) << 2;
  const int tm = (t & 15) << 2;
  const int tn = (t >> 4) << 2;
  float acc[4][4] = {};
  for (int k0 = 0; k0 < DM; k0 += 16) {
    __syncthreads();
    float4 a = *(const float4*)&Q[(size_t)(m0 + lm) * DM + k0 + lk];
    As[lk + 0][lm] = a.x; As[lk + 1][lm] = a.y; As[lk + 2][lm] = a.z; As[lk + 3][lm] = a.w;
    float4 b = *(const float4*)&W1[(size_t)(n0 + lm) * 2048 + k0 + lk];
    Bs[lk + 0][lm] = b.x; Bs[lk + 1][lm] = b.y; Bs[lk + 2][lm] = b.z; Bs[lk + 3][lm] = b.w;
    __syncthreads();
    #pragma unroll
    for (int kk = 0; kk < 16; ++kk) {
      float av0 = As[kk][tm], av1 = As[kk][tm + 1], av2 = As[kk][tm + 2], av3 = As[kk][tm + 3];
      float bv0 = Bs[kk][tn], bv1 = Bs[kk][tn + 1], bv2 = Bs[kk][tn + 2], bv3 = Bs[kk][tn + 3];
      acc[0][0] += av0 * bv0; acc[0][1] += av0 * bv1; acc[0][2] += av0 * bv2; acc[0][3] += av0 * bv3;
      acc[1][0] += av1 * bv0; acc[1][1] += av1 * bv1; acc[1][2] += av1 * bv2; acc[1][3] += av1 * bv3;
      acc[2][0] += av2 * bv0; acc[2][1] += av2 * bv1; acc[2][2] += av2 * bv2; acc[2][3] += av2 * bv3;
      acc[3][0] += av3 * bv0; acc[3][1] += av3 * bv1; acc[3][2] += av3 * bv2; acc[3][3] += av3 * bv3;
    }
  }
  #pragma unroll
  for (int i = 0; i < 4; ++i)
    #pragma unroll
    for (int jj = 0; jj < 4; ++jj)
      preQ[(size_t)(m0 + tm + i) * DM + n0 + tn + jj] = acc[i][jj] + b1[n0 + tn + jj];
}

// ---------------- persistent ticket-driven dataflow ----------------
__global__ __launch_bounds__(256) void k_dataflow(
    const float* __restrict__ W1, const int* __restrict__ dep_idx,
    const int* __restrict__ dep_mask, const float* __restrict__ preQ,
    float* __restrict__ hP, float* __restrict__ gP, int* __restrict__ meta) {
  __shared__ int s_lo[MAXL];
  __shared__ int s_t, s_l, s_kind, s_idx;
  const int nL = meta[MI_NLEV];
  const int total = meta[MI_TOTAL];
  for (int i = threadIdx.x; i <= nL; i += 256) s_lo[i] = meta[MI_LO + i];
  __syncthreads();
  for (;;) {
    if (threadIdx.x == 0) {
      int t = __hip_atomic_fetch_add(&meta[MI_TICKET], 1, __ATOMIC_RELAXED, __HIP_MEMORY_SCOPE_AGENT);
      s_t = t;
      if (t < total) {
        int lo = 0, hi = nL - 1;
        while (lo < hi) {
          int mid = (lo + hi + 1) >> 1;
          if (s_lo[mid] + mid * NB <= t) lo = mid; else hi = mid - 1;
        }
        int local = t - (s_lo[lo] + lo * NB);
        int sz = s_lo[lo + 1] - s_lo[lo];
        s_l = lo;
        s_kind = (local < sz) ? 0 : 1;
        s_idx = (local < sz) ? (s_lo[lo] + local) : (local - sz);
      }
    }
    __syncthreads();
    if (s_t >= total) break;
    const int l = s_l;
    if (s_kind == 0) {
      // ---- A-item: h[row] = gelu(preQ[node] + mean of dep g-rows) ----
      const int row = s_idx;
      const int node = meta[MI_PERM + row];
      if (threadIdx.x == 0 && l > 0) {
        int* p = &meta[MI_GDONE + l - 1];
        while (__hip_atomic_load(p, __ATOMIC_RELAXED, __HIP_MEMORY_SCOPE_AGENT) < NB)
          __builtin_amdgcn_s_sleep(2);
        (void)__hip_atomic_load(p, __ATOMIC_ACQUIRE, __HIP_MEMORY_SCOPE_AGENT);
      }
      __syncthreads();
      int nd = 0; int dpos[MD];
      #pragma unroll
      for (int d = 0; d < MD; ++d) {
        if (dep_mask[node * MD + d]) dpos[nd++] = meta[MI_POS + dep_idx[node * MD + d]];
      }
      const float inv = nd ? 1.0f / (float)nd : 0.0f;
      const int k = threadIdx.x << 2;
      float4 pq = *(const float4*)&preQ[(size_t)node * DM + k];
      float sx = 0.f, sy = 0.f, sz2 = 0.f, sw = 0.f;
      for (int d = 0; d < nd; ++d) {
        float4 g = *(const float4*)&gP[(size_t)dpos[d] * DM + k];
        sx += g.x; sy += g.y; sz2 += g.z; sw += g.w;
      }
      float4 hv;
      hv.x = gelu_f(pq.x + sx * inv);
      hv.y = gelu_f(pq.y + sy * inv);
      hv.z = gelu_f(pq.z + sz2 * inv);
      hv.w = gelu_f(pq.w + sw * inv);
      *(float4*)&hP[(size_t)row * DM + k] = hv;
      __syncthreads();
      if (threadIdx.x == 0)
        __hip_atomic_fetch_add(&meta[MI_HDONE + l], 1, __ATOMIC_RELEASE, __HIP_MEMORY_SCOPE_AGENT);
    } else {
      // ---- B-item: g[rows of level, 8 cols] = hP rows @ W1c[cols]^T ----
      const int c = s_idx;
      const int lo = s_lo[l], hi2 = s_lo[l + 1];
      const int sz = hi2 - lo;
      if (threadIdx.x == 0) {
        int* p = &meta[MI_HDONE + l];
        while (__hip_atomic_load(p, __ATOMIC_RELAXED, __HIP_MEMORY_SCOPE_AGENT) < sz)
          __builtin_amdgcn_s_sleep(2);
        (void)__hip_atomic_load(p, __ATOMIC_ACQUIRE, __HIP_MEMORY_SCOPE_AGENT);
      }
      __syncthreads();
      const int lane = threadIdx.x & 63;
      const int w = threadIdx.x >> 6;
      const int jo = lane >> 3, ks = lane & 7;
      const int j = c * TC + jo;
      const float* wrow = W1 + (size_t)j * 2048 + 1024 + ks * 128;
      for (int r = lo + w; r < hi2; r += 4) {
        const float* hrow = hP + (size_t)r * DM + ks * 128;
        float acc = 0.f;
        #pragma unroll
        for (int u = 0; u < 32; ++u) {
          float4 wv = *(const float4*)&wrow[u * 4];
          float4 hv = *(const float4*)&hrow[u * 4];
          acc += wv.x * hv.x + wv.y * hv.y + wv.z * hv.z + wv.w * hv.w;
        }
        acc += __shfl_xor(acc, 1);
        acc += __shfl_xor(acc, 2);
        acc += __shfl_xor(acc, 4);
        if (ks == 0) gP[(size_t)r * DM + j] = acc;
      }
      __syncthreads();
      if (threadIdx.x == 0)
        __hip_atomic_fetch_add(&meta[MI_GDONE + l], 1, __ATOMIC_RELEASE, __HIP_MEMORY_SCOPE_AGENT);
    }
  }
}

// ---------------- logits = W2 @ h[4095] + b2 ----------------
__global__ __launch_bounds__(256) void k_logits(
    const float* __restrict__ W2, const float* __restrict__ b2,
    const float* __restrict__ hP, const int* __restrict__ meta, float* __restrict__ out) {
  __shared__ float red[256];
  const int t = threadIdx.x;
  const int row = meta[MI_POS + (NN - 1)];
  const int j = t >> 2, kc = t & 3;
  const float* h = hP + (size_t)row * DM;
  const float* wr = W2 + (size_t)j * DM;
  float acc = 0.f;
  for (int k = kc * 256; k < kc * 256 + 256; k += 4) {
    float4 hv = *(const float4*)&h[k];
    float4 wv = *(const float4*)&wr[k];
    acc += hv.x * wv.x + hv.y * wv.y + hv.z * wv.z + hv.w * wv.w;
  }
  red[t] = acc;
  __syncthreads();
  if (kc == 0) out[j] = red[t] + red[t + 1] + red[t + 2] + red[t + 3] + b2[j];
}

extern "C" void kernel_launch(void* const* d_in, const int* in_sizes, int n_in,
                              void* d_out, int out_size, void* d_ws, size_t ws_size,
                              hipStream_t stream) {
  const float* Q        = (const float*)d_in[0];
  const float* W1       = (const float*)d_in[1];
  const float* b1       = (const float*)d_in[2];
  const float* W2       = (const float*)d_in[3];
  const float* b2       = (const float*)d_in[4];
  const int*   dep_idx  = (const int*)d_in[5];
  const int*   dep_mask = (const int*)d_in[6];

  float* wsf  = (float*)d_ws;
  float* preQ = wsf;                         // 16 MB
  float* hP   = wsf + (size_t)NN * DM;       // 16 MB (level-permuted rows)
  float* gP   = wsf + 2ull * NN * DM;        // 16 MB (level-permuted rows)
  int*   meta = (int*)((char*)d_ws + 3ull * NN * DM * sizeof(float));
  float* out  = (float*)d_out;

  k_prologue<<<dim3(1), dim3(1024), 0, stream>>>(dep_idx, dep_mask, meta);
  k_preq<<<dim3(DM / 64, NN / 64), dim3(256), 0, stream>>>(Q, W1, b1, preQ);
  k_dataflow<<<dim3(GBLK), dim3(256), 0, stream>>>(W1, dep_idx, dep_mask, preQ, hP, gP, meta);
  k_logits<<<dim3(1), dim3(256), 0, stream>>>(W2, b2, hP, meta, out);
}

// Round 2
// 3753.408 us; speedup vs baseline: 2.4488x; 2.4488x over previous
//
#include <hip/hip_runtime.h>

#define NN 4096
#define DM 1024
#define MD 8
#define NCLS 64
#define NW 255          // worker blocks
#define GB (NW + 1)     // + 1 coordinator block
#define NCH 128         // B-phase chunks (8 cols each)
#define MAXL 4097

// meta layout (int offsets within meta region of d_ws)
#define MI_NLEV 0
#define MI_DOOR 8
#define MI_LO 16        // levelOffset[nL+1]
#define MI_POS 8192     // pos[4096]  (node -> permuted row)
#define MI_PERM 12288   // perm[4096] (row -> node)
#define MI_ARRIVE 16384 // arrive[NW]

__device__ __forceinline__ float gelu_f(float x) {
  return 0.5f * x * (1.0f + erff(x * 0.70710678118654752440f));
}

// ---------------- prologue: levels + counting sort + barrier reset ----------------
__global__ __launch_bounds__(1024) void k_prologue(
    const int* __restrict__ dep_idx, const int* __restrict__ dep_mask,
    int* __restrict__ meta) {
  __shared__ int lvl[NN];
  __shared__ int cnt[NN];
  __shared__ int s_changed, s_max;
  const int t = threadIdx.x;
  // register-cache this thread's 4 nodes' deps
  int di[4][MD];
  int dmsk[4];
  #pragma unroll
  for (int u = 0; u < 4; ++u) {
    const int i = t * 4 + u;
    int mbits = 0;
    #pragma unroll
    for (int d = 0; d < MD; ++d) {
      di[u][d] = dep_idx[i * MD + d];
      mbits |= (dep_mask[i * MD + d] ? (1 << d) : 0);
    }
    dmsk[u] = mbits;
  }
  for (int i = t; i < NN; i += 1024) { lvl[i] = 0; cnt[i] = 0; }
  if (t == 0) s_max = 0;
  __syncthreads();
  // monotone sweeps to longest-path levels
  for (int it = 0; it < NN; ++it) {
    if (t == 0) s_changed = 0;
    __syncthreads();
    #pragma unroll
    for (int u = 0; u < 4; ++u) {
      const int i = t * 4 + u;
      int m = 0;
      #pragma unroll
      for (int d = 0; d < MD; ++d) {
        if (dmsk[u] & (1 << d)) {
          int l = lvl[di[u][d]] + 1;
          m = m > l ? m : l;
        }
      }
      if (m > lvl[i]) { lvl[i] = m; s_changed = 1; }
    }
    __syncthreads();
    if (!s_changed) break;
  }
  for (int i = t; i < NN; i += 1024) { atomicAdd(&cnt[lvl[i]], 1); atomicMax(&s_max, lvl[i]); }
  __syncthreads();
  const int nL = s_max + 1;
  if (t == 0) {
    int off = 0;
    for (int l = 0; l < nL; ++l) { int c = cnt[l]; meta[MI_LO + l] = off; cnt[l] = off; off += c; }
    meta[MI_LO + nL] = off;
    meta[MI_NLEV] = nL;
    meta[MI_DOOR] = 0;
  }
  __syncthreads();
  for (int i = t; i < NN; i += 1024) {
    int r = atomicAdd(&cnt[lvl[i]], 1);
    meta[MI_POS + i] = r;
    meta[MI_PERM + r] = i;
  }
  for (int i = t; i < NW; i += 1024) meta[MI_ARRIVE + i] = 0;
}

// ---------------- preQ = Q @ W1[:, :1024]^T + b1  (fp32 tiled GEMM) ----------------
__global__ __launch_bounds__(256) void k_preq(
    const float* __restrict__ Q, const float* __restrict__ W1,
    const float* __restrict__ b1, float* __restrict__ preQ) {
  __shared__ float As[16][65];
  __shared__ float Bs[16][65];
  const int t = threadIdx.x;
  const int m0 = blockIdx.y * 64, n0 = blockIdx.x * 64;
  const int lm = t >> 2;
  const int lk = (t & 3) << 2;
  const int tm = (t & 15) << 2;
  const int tn = (t >> 4) << 2;
  float acc[4][4] = {};
  for (int k0 = 0; k0 < DM; k0 += 16) {
    __syncthreads();
    float4 a = *(const float4*)&Q[(size_t)(m0 + lm) * DM + k0 + lk];
    As[lk + 0][lm] = a.x; As[lk + 1][lm] = a.y; As[lk + 2][lm] = a.z; As[lk + 3][lm] = a.w;
    float4 b = *(const float4*)&W1[(size_t)(n0 + lm) * 2048 + k0 + lk];
    Bs[lk + 0][lm] = b.x; Bs[lk + 1][lm] = b.y; Bs[lk + 2][lm] = b.z; Bs[lk + 3][lm] = b.w;
    __syncthreads();
    #pragma unroll
    for (int kk = 0; kk < 16; ++kk) {
      float av0 = As[kk][tm], av1 = As[kk][tm + 1], av2 = As[kk][tm + 2], av3 = As[kk][tm + 3];
      float bv0 = Bs[kk][tn], bv1 = Bs[kk][tn + 1], bv2 = Bs[kk][tn + 2], bv3 = Bs[kk][tn + 3];
      acc[0][0] += av0 * bv0; acc[0][1] += av0 * bv1; acc[0][2] += av0 * bv2; acc[0][3] += av0 * bv3;
      acc[1][0] += av1 * bv0; acc[1][1] += av1 * bv1; acc[1][2] += av1 * bv2; acc[1][3] += av1 * bv3;
      acc[2][0] += av2 * bv0; acc[2][1] += av2 * bv1; acc[2][2] += av2 * bv2; acc[2][3] += av2 * bv3;
      acc[3][0] += av3 * bv0; acc[3][1] += av3 * bv1; acc[3][2] += av3 * bv2; acc[3][3] += av3 * bv3;
    }
  }
  #pragma unroll
  for (int i = 0; i < 4; ++i)
    #pragma unroll
    for (int jj = 0; jj < 4; ++jj)
      preQ[(size_t)(m0 + tm + i) * DM + n0 + tn + jj] = acc[i][jj] + b1[n0 + tn + jj];
}

// ---------------- persistent level-synchronous dataflow ----------------
__global__ __launch_bounds__(256) void k_levels(
    const float* __restrict__ W1, const int* __restrict__ dep_idx,
    const int* __restrict__ dep_mask, const float* __restrict__ preQ,
    float* __restrict__ hP, float* __restrict__ gP, int* __restrict__ meta) {
  const int tid = threadIdx.x;
  const int nL = meta[MI_NLEV];

  // ---- coordinator block: scan arrive[] (stores only, no RMW), ring doorbell ----
  if (blockIdx.x == NW) {
    if (tid < 64) {
      const int P = 2 * nL;
      for (int ph = 1; ph <= P; ++ph) {
        for (;;) {
          int m = ph;
          #pragma unroll
          for (int u = 0; u < 4; ++u) {
            int idx = tid + u * 64;
            if (idx < NW) {
              int v = __hip_atomic_load(&meta[MI_ARRIVE + idx], __ATOMIC_RELAXED, __HIP_MEMORY_SCOPE_AGENT);
              m = v < m ? v : m;
            }
          }
          #pragma unroll
          for (int off = 1; off < 64; off <<= 1) {
            int o = __shfl_xor(m, off);
            m = o < m ? o : m;
          }
          if (m >= ph) break;
        }
        if (tid == 0) {
          __threadfence();
          __hip_atomic_store(&meta[MI_DOOR], ph, __ATOMIC_RELAXED, __HIP_MEMORY_SCOPE_AGENT);
        }
      }
    }
    return;
  }

  // ---- worker blocks ----
  const int wb = blockIdx.x;
  __shared__ int s_lo[MAXL];
  __shared__ float WL[8 * 1024];
  for (int i = tid; i <= nL; i += 256) s_lo[i] = meta[MI_LO + i];
  __syncthreads();

#define WBAR(ph) do { \
    __syncthreads(); \
    if (tid == 0) { \
      __threadfence(); \
      __hip_atomic_store(&meta[MI_ARRIVE + wb], (ph), __ATOMIC_RELAXED, __HIP_MEMORY_SCOPE_AGENT); \
      while (__hip_atomic_load(&meta[MI_DOOR], __ATOMIC_RELAXED, __HIP_MEMORY_SCOPE_AGENT) < (ph)) \
        __builtin_amdgcn_s_sleep(1); \
      __threadfence(); \
    } \
    __syncthreads(); \
  } while (0)

  for (int l = 0; l < nL; ++l) {
    const int lo = s_lo[l], hi = s_lo[l + 1];

    // ---- A-phase: h[row] = gelu(preQ[node] + mean of dep g-rows) ----
    for (int r = lo + wb; r < hi; r += NW) {
      const int node = meta[MI_PERM + r];
      int nd = 0; int dpos[MD];
      #pragma unroll
      for (int d = 0; d < MD; ++d) {
        if (dep_mask[node * MD + d]) dpos[nd++] = meta[MI_POS + dep_idx[node * MD + d]];
      }
      const float inv = nd ? 1.0f / (float)nd : 0.0f;
      const int k = tid << 2;
      float4 pq = *(const float4*)&preQ[(size_t)node * DM + k];
      float sx = 0.f, sy = 0.f, sz2 = 0.f, sw = 0.f;
      for (int d = 0; d < nd; ++d) {
        float4 g = *(const float4*)&gP[(size_t)dpos[d] * DM + k];
        sx += g.x; sy += g.y; sz2 += g.z; sw += g.w;
      }
      float4 hv;
      hv.x = gelu_f(pq.x + sx * inv);
      hv.y = gelu_f(pq.y + sy * inv);
      hv.z = gelu_f(pq.z + sz2 * inv);
      hv.w = gelu_f(pq.w + sw * inv);
      *(float4*)&hP[(size_t)r * DM + k] = hv;
    }
    WBAR(2 * l + 1);

    // ---- B-phase: g[rows, 8-col chunk] = hP rows @ W1c[cols]^T ----
    for (int c = wb; c < NCH; c += NW) {
      const int j0 = c * 8;
      // stage 8 W1c rows (cols of the GEMM) into LDS
      for (int v = tid; v < 2048; v += 256) {
        const int jj = v >> 8, k4 = (v & 255) << 2;
        *(float4*)&WL[jj * 1024 + k4] = *(const float4*)&W1[(size_t)(j0 + jj) * 2048 + 1024 + k4];
      }
      __syncthreads();
      const int col = tid >> 5, s = tid & 31;
      for (int r = lo; r < hi; ++r) {
        const float* hrow = hP + (size_t)r * DM;
        float acc = 0.f;
        #pragma unroll
        for (int tt = 0; tt < 8; ++tt) {
          const int k = tt * 128 + (s << 2);
          float4 hv = *(const float4*)&hrow[k];
          float4 wv = *(const float4*)&WL[col * 1024 + k];
          acc += hv.x * wv.x + hv.y * wv.y + hv.z * wv.z + hv.w * wv.w;
        }
        acc += __shfl_xor(acc, 1);
        acc += __shfl_xor(acc, 2);
        acc += __shfl_xor(acc, 4);
        acc += __shfl_xor(acc, 8);
        acc += __shfl_xor(acc, 16);
        if (s == 0) gP[(size_t)r * DM + j0 + col] = acc;
      }
      __syncthreads();
    }
    WBAR(2 * l + 2);
  }
#undef WBAR
}

// ---------------- logits = W2 @ h[4095] + b2 ----------------
__global__ __launch_bounds__(256) void k_logits(
    const float* __restrict__ W2, const float* __restrict__ b2,
    const float* __restrict__ hP, const int* __restrict__ meta, float* __restrict__ out) {
  __shared__ float red[256];
  const int t = threadIdx.x;
  const int row = meta[MI_POS + (NN - 1)];
  const int j = t >> 2, kc = t & 3;
  const float* h = hP + (size_t)row * DM;
  const float* wr = W2 + (size_t)j * DM;
  float acc = 0.f;
  for (int k = kc * 256; k < kc * 256 + 256; k += 4) {
    float4 hv = *(const float4*)&h[k];
    float4 wv = *(const float4*)&wr[k];
    acc += hv.x * wv.x + hv.y * wv.y + hv.z * wv.z + hv.w * wv.w;
  }
  red[t] = acc;
  __syncthreads();
  if (kc == 0) out[j] = red[t] + red[t + 1] + red[t + 2] + red[t + 3] + b2[j];
}

extern "C" void kernel_launch(void* const* d_in, const int* in_sizes, int n_in,
                              void* d_out, int out_size, void* d_ws, size_t ws_size,
                              hipStream_t stream) {
  const float* Q        = (const float*)d_in[0];
  const float* W1       = (const float*)d_in[1];
  const float* b1       = (const float*)d_in[2];
  const float* W2       = (const float*)d_in[3];
  const float* b2       = (const float*)d_in[4];
  const int*   dep_idx  = (const int*)d_in[5];
  const int*   dep_mask = (const int*)d_in[6];

  float* wsf  = (float*)d_ws;
  float* preQ = wsf;                         // 16 MB
  float* hP   = wsf + (size_t)NN * DM;       // 16 MB (level-permuted rows)
  float* gP   = wsf + 2ull * NN * DM;        // 16 MB (level-permuted rows)
  int*   meta = (int*)((char*)d_ws + 3ull * NN * DM * sizeof(float));
  float* out  = (float*)d_out;

  k_prologue<<<dim3(1), dim3(1024), 0, stream>>>(dep_idx, dep_mask, meta);
  k_preq<<<dim3(DM / 64, NN / 64), dim3(256), 0, stream>>>(Q, W1, b1, preQ);
  k_levels<<<dim3(GB), dim3(256), 0, stream>>>(W1, dep_idx, dep_mask, preQ, hP, gP, meta);
  k_logits<<<dim3(1), dim3(256), 0, stream>>>(W2, b2, hP, meta, out);
}

// Round 3
// 2022.444 us; speedup vs baseline: 4.5446x; 1.8559x over previous
//
#include <hip/hip_runtime.h>

#define NN 4096
#define DM 1024
#define MD 8
#define NW 256          // worker blocks = column slices
#define NCOL 4          // columns per block (NW*NCOL = DM)
#define MAXL 4097

// meta layout (int offsets within meta region of d_ws)
#define MI_NLEV 0
#define MI_ROOTPOS 1
#define MI_ARRIVE 8     // arrive[NW]
#define MI_LO 512       // levelOffset[nL+1]
#define MI_PERM 8192    // perm[4096] (row -> node)
#define MI_DCNT 12288   // dep count per permuted row
#define MI_CONS 16384   // consumed flag per permuted row
#define MI_INV 20480    // (float) 1/nd per permuted row
#define MI_DPOS 24576   // dpos[4096*8]: permuted dep rows (padded with 0)

__device__ __forceinline__ float gelu_f(float x) {
  return 0.5f * x * (1.0f + erff(x * 0.70710678118654752440f));
}

// ---------------- prologue: levels (chunked Gauss-Seidel), counting sort,
// ---------------- permuted dep lists, consumed flags, barrier reset ----------------
__global__ __launch_bounds__(1024) void k_prologue(
    const int* __restrict__ dep_idx, const int* __restrict__ dep_mask,
    int* __restrict__ meta) {
  __shared__ int lvl[NN];
  __shared__ int cnt[NN];
  __shared__ int pos[NN];
  __shared__ int cons[NN];
  __shared__ int s_changed, s_max;
  const int t = threadIdx.x;
  for (int i = t; i < NN; i += 1024) { lvl[i] = 0; cnt[i] = 0; cons[i] = 0; }
  if (t == 0) s_max = 0;
  __syncthreads();
  // 4 chunks of 1024 nodes, processed in index order; deps < i so levels are
  // final after each chunk stabilizes.
  for (int u = 0; u < 4; ++u) {
    const int i = u * 1024 + t;
    const int4 d0 = *(const int4*)&dep_idx[i * MD];
    const int4 d1 = *(const int4*)&dep_idx[i * MD + 4];
    const int4 m0 = *(const int4*)&dep_mask[i * MD];
    const int4 m1 = *(const int4*)&dep_mask[i * MD + 4];
    int my = 0;
    for (;;) {
      if (t == 0) s_changed = 0;
      __syncthreads();
      int m = 0;
      if (m0.x) { int l = lvl[d0.x] + 1; m = m > l ? m : l; }
      if (m0.y) { int l = lvl[d0.y] + 1; m = m > l ? m : l; }
      if (m0.z) { int l = lvl[d0.z] + 1; m = m > l ? m : l; }
      if (m0.w) { int l = lvl[d0.w] + 1; m = m > l ? m : l; }
      if (m1.x) { int l = lvl[d1.x] + 1; m = m > l ? m : l; }
      if (m1.y) { int l = lvl[d1.y] + 1; m = m > l ? m : l; }
      if (m1.z) { int l = lvl[d1.z] + 1; m = m > l ? m : l; }
      if (m1.w) { int l = lvl[d1.w] + 1; m = m > l ? m : l; }
      if (m > my) { my = m; lvl[i] = m; s_changed = 1; }
      __syncthreads();
      if (!s_changed) break;
    }
    // mark consumed (plain idempotent LDS stores)
    if (m0.x) cons[d0.x] = 1;
    if (m0.y) cons[d0.y] = 1;
    if (m0.z) cons[d0.z] = 1;
    if (m0.w) cons[d0.w] = 1;
    if (m1.x) cons[d1.x] = 1;
    if (m1.y) cons[d1.y] = 1;
    if (m1.z) cons[d1.z] = 1;
    if (m1.w) cons[d1.w] = 1;
    __syncthreads();
  }
  for (int i = t; i < NN; i += 1024) { atomicAdd(&cnt[lvl[i]], 1); atomicMax(&s_max, lvl[i]); }
  __syncthreads();
  const int nL = s_max + 1;
  if (t == 0) {
    int off = 0;
    for (int l = 0; l < nL; ++l) { int c = cnt[l]; meta[MI_LO + l] = off; cnt[l] = off; off += c; }
    meta[MI_LO + nL] = off;
    meta[MI_NLEV] = nL;
  }
  __syncthreads();
  for (int i = t; i < NN; i += 1024) pos[i] = atomicAdd(&cnt[lvl[i]], 1);
  __syncthreads();
  for (int i = t; i < NN; i += 1024) {
    const int r = pos[i];
    meta[MI_PERM + r] = i;
    int nd = 0;
    #pragma unroll
    for (int d = 0; d < MD; ++d) {
      if (dep_mask[i * MD + d]) { meta[MI_DPOS + r * MD + nd] = pos[dep_idx[i * MD + d]]; ++nd; }
    }
    for (int d = nd; d < MD; ++d) meta[MI_DPOS + r * MD + d] = 0;
    meta[MI_DCNT + r] = nd;
    ((float*)meta)[MI_INV + r] = nd ? 1.0f / (float)nd : 0.0f;
    meta[MI_CONS + r] = cons[i];
  }
  if (t == 0) meta[MI_ROOTPOS] = pos[NN - 1];
  for (int i = t; i < NW; i += 1024) meta[MI_ARRIVE + i] = 0;
}

// ---------------- preQ = Q @ W1[:, :1024]^T + b1  (fp32 tiled GEMM) ----------------
__global__ __launch_bounds__(256) void k_preq(
    const float* __restrict__ Q, const float* __restrict__ W1,
    const float* __restrict__ b1, float* __restrict__ preQ) {
  __shared__ float As[16][65];
  __shared__ float Bs[16][65];
  const int t = threadIdx.x;
  const int m0 = blockIdx.y * 64, n0 = blockIdx.x * 64;
  const int lm = t >> 2;
  const int lk = (t & 3) << 2;
  const int tm = (t & 15) << 2;
  const int tn = (t >> 4) << 2;
  float acc[4][4] = {};
  for (int k0 = 0; k0 < DM; k0 += 16) {
    __syncthreads();
    float4 a = *(const float4*)&Q[(size_t)(m0 + lm) * DM + k0 + lk];
    As[lk + 0][lm] = a.x; As[lk + 1][lm] = a.y; As[lk + 2][lm] = a.z; As[lk + 3][lm] = a.w;
    float4 b = *(const float4*)&W1[(size_t)(n0 + lm) * 2048 + k0 + lk];
    Bs[lk + 0][lm] = b.x; Bs[lk + 1][lm] = b.y; Bs[lk + 2][lm] = b.z; Bs[lk + 3][lm] = b.w;
    __syncthreads();
    #pragma unroll
    for (int kk = 0; kk < 16; ++kk) {
      float av0 = As[kk][tm], av1 = As[kk][tm + 1], av2 = As[kk][tm + 2], av3 = As[kk][tm + 3];
      float bv0 = Bs[kk][tn], bv1 = Bs[kk][tn + 1], bv2 = Bs[kk][tn + 2], bv3 = Bs[kk][tn + 3];
      acc[0][0] += av0 * bv0; acc[0][1] += av0 * bv1; acc[0][2] += av0 * bv2; acc[0][3] += av0 * bv3;
      acc[1][0] += av1 * bv0; acc[1][1] += av1 * bv1; acc[1][2] += av1 * bv2; acc[1][3] += av1 * bv3;
      acc[2][0] += av2 * bv0; acc[2][1] += av2 * bv1; acc[2][2] += av2 * bv2; acc[2][3] += av2 * bv3;
      acc[3][0] += av3 * bv0; acc[3][1] += av3 * bv1; acc[3][2] += av3 * bv2; acc[3][3] += av3 * bv3;
    }
  }
  #pragma unroll
  for (int i = 0; i < 4; ++i)
    #pragma unroll
    for (int jj = 0; jj < 4; ++jj)
      preQ[(size_t)(m0 + tm + i) * DM + n0 + tn + jj] = acc[i][jj] + b1[n0 + tn + jj];
}

// ---------------- persistent column-sliced level dataflow (1 barrier/level) ----------------
__global__ __launch_bounds__(256) void k_levels(
    const float* __restrict__ W1, const float* __restrict__ preQ,
    float* __restrict__ hP, float* __restrict__ gP, int* __restrict__ meta) {
  const int tid = threadIdx.x;
  const int wb = blockIdx.x;
  const int c0 = wb * NCOL;
  const int wave = tid >> 6, lane = tid & 63;
  const int nL = meta[MI_NLEV];
  __shared__ int s_lo[MAXL];
  __shared__ float WL[NCOL * DM];   // this block's 4 rows of W1c, resident all levels
  for (int i = tid; i <= nL; i += 256) s_lo[i] = meta[MI_LO + i];
  for (int v = tid; v < NCOL * 256; v += 256) {
    const int jj = v >> 8, k4 = (v & 255) << 2;
    *(float4*)&WL[jj * DM + k4] = *(const float4*)&W1[(size_t)(c0 + jj) * 2048 + 1024 + k4];
  }
  __syncthreads();
  const float* invA = (const float*)&meta[MI_INV];

  for (int l = 0; l < nL; ++l) {
    const int lo = s_lo[l], hi = s_lo[l + 1];

    // ---- A-phase (own columns only; g deps are this block's own prior writes) ----
    {
      const int r16 = lane >> 2, c = lane & 3;
      for (int r = lo + wave * 16 + r16; r < hi; r += 64) {
        const int node = meta[MI_PERM + r];
        const int nd = meta[MI_DCNT + r];
        const float iv = invA[r];
        const int4 p0 = *(const int4*)&meta[MI_DPOS + r * MD];
        const int4 p1 = *(const int4*)&meta[MI_DPOS + r * MD + 4];
        const int dps[8] = {p0.x, p0.y, p0.z, p0.w, p1.x, p1.y, p1.z, p1.w};
        float s = 0.f;
        #pragma unroll
        for (int d = 0; d < MD; ++d) {
          float v = gP[(size_t)dps[d] * DM + c0 + c];
          s += (d < nd) ? v : 0.f;
        }
        const float x = preQ[(size_t)node * DM + c0 + c] + s * iv;
        hP[(size_t)r * DM + c0 + c] = gelu_f(x);
      }
    }

    // ---- all-to-all barrier: h(l) complete ----
    __syncthreads();
    if (tid == 0) {
      __threadfence();
      __hip_atomic_store(&meta[MI_ARRIVE + wb], l + 1, __ATOMIC_RELAXED, __HIP_MEMORY_SCOPE_AGENT);
    }
    if (tid < 64) {
      for (;;) {
        int m = 1 << 30;
        #pragma unroll
        for (int u = 0; u < 4; ++u) {
          int v = __hip_atomic_load(&meta[MI_ARRIVE + tid * 4 + u], __ATOMIC_RELAXED, __HIP_MEMORY_SCOPE_AGENT);
          m = v < m ? v : m;
        }
        #pragma unroll
        for (int off = 1; off < 64; off <<= 1) {
          int o = __shfl_xor(m, off);
          m = o < m ? o : m;
        }
        if (m >= l + 1) break;
        __builtin_amdgcn_s_sleep(1);
      }
      __threadfence();
    }
    __syncthreads();

    // ---- B-phase: wave-per-row, g[r, own 4 cols] = W1c_slice @ h[r,:] ----
    for (int r = lo + wave; r < hi; r += 4) {
      if (!meta[MI_CONS + r]) continue;
      const float4* h4 = (const float4*)&hP[(size_t)r * DM];
      const float4 hv0 = h4[lane], hv1 = h4[64 + lane], hv2 = h4[128 + lane], hv3 = h4[192 + lane];
      float res = 0.f;
      #pragma unroll
      for (int cc = 0; cc < NCOL; ++cc) {
        const float4* w4 = (const float4*)&WL[cc * DM];
        const float4 w0 = w4[lane], w1 = w4[64 + lane], w2 = w4[128 + lane], w3 = w4[192 + lane];
        float a = hv0.x * w0.x + hv0.y * w0.y + hv0.z * w0.z + hv0.w * w0.w
                + hv1.x * w1.x + hv1.y * w1.y + hv1.z * w1.z + hv1.w * w1.w
                + hv2.x * w2.x + hv2.y * w2.y + hv2.z * w2.z + hv2.w * w2.w
                + hv3.x * w3.x + hv3.y * w3.y + hv3.z * w3.z + hv3.w * w3.w;
        #pragma unroll
        for (int off = 1; off < 64; off <<= 1) a += __shfl_xor(a, off);
        if (lane == cc) res = a;
      }
      if (lane < NCOL) gP[(size_t)r * DM + c0 + lane] = res;
    }
    __syncthreads();   // own g writes visible block-wide for next level's A
  }
}

// ---------------- logits = W2 @ h[root] + b2 ----------------
__global__ __launch_bounds__(256) void k_logits(
    const float* __restrict__ W2, const float* __restrict__ b2,
    const float* __restrict__ hP, const int* __restrict__ meta, float* __restrict__ out) {
  __shared__ float red[256];
  const int t = threadIdx.x;
  const int row = meta[MI_ROOTPOS];
  const int j = t >> 2, kc = t & 3;
  const float* h = hP + (size_t)row * DM;
  const float* wr = W2 + (size_t)j * DM;
  float acc = 0.f;
  for (int k = kc * 256; k < kc * 256 + 256; k += 4) {
    float4 hv = *(const float4*)&h[k];
    float4 wv = *(const float4*)&wr[k];
    acc += hv.x * wv.x + hv.y * wv.y + hv.z * wv.z + hv.w * wv.w;
  }
  red[t] = acc;
  __syncthreads();
  if (kc == 0) out[j] = red[t] + red[t + 1] + red[t + 2] + red[t + 3] + b2[j];
}

extern "C" void kernel_launch(void* const* d_in, const int* in_sizes, int n_in,
                              void* d_out, int out_size, void* d_ws, size_t ws_size,
                              hipStream_t stream) {
  const float* Q        = (const float*)d_in[0];
  const float* W1       = (const float*)d_in[1];
  const float* b1       = (const float*)d_in[2];
  const float* W2       = (const float*)d_in[3];
  const float* b2       = (const float*)d_in[4];
  const int*   dep_idx  = (const int*)d_in[5];
  const int*   dep_mask = (const int*)d_in[6];

  float* wsf  = (float*)d_ws;
  float* preQ = wsf;                         // 16 MB
  float* hP   = wsf + (size_t)NN * DM;       // 16 MB (level-permuted rows)
  float* gP   = wsf + 2ull * NN * DM;        // 16 MB (level-permuted rows)
  int*   meta = (int*)((char*)d_ws + 3ull * NN * DM * sizeof(float));
  float* out  = (float*)d_out;

  k_prologue<<<dim3(1), dim3(1024), 0, stream>>>(dep_idx, dep_mask, meta);
  k_preq<<<dim3(DM / 64, NN / 64), dim3(256), 0, stream>>>(Q, W1, b1, preQ);
  k_levels<<<dim3(NW), dim3(256), 0, stream>>>(W1, preQ, hP, gP, meta);
  k_logits<<<dim3(1), dim3(256), 0, stream>>>(W2, b2, hP, meta, out);
}

// Round 4
// 1341.332 us; speedup vs baseline: 6.8523x; 1.5078x over previous
//
#include <hip/hip_runtime.h>

#define NN 4096
#define DM 1024
#define MD 8
#define NW 256          // worker blocks = column slices
#define NCOL 4          // columns per block (NW*NCOL = DM)
#define MAXL 4097

// meta layout (int offsets within meta region of d_ws)
#define MI_NLEV 0
#define MI_ROOTPOS 1
#define MI_ARRIVE 8     // arrive[NW]
#define MI_LO 512       // levelOffset[nL+1]
#define MI_PERM 8192    // perm[4096] (row -> node)
#define MI_DCNT 12288   // dep count per permuted row
#define MI_CONS 16384   // consumed flag per permuted row
#define MI_INV 20480    // (float) 1/nd per permuted row
#define MI_DPOS 24576   // dpos[4096*8]: permuted dep rows (padded with 0)

__device__ __forceinline__ float gelu_f(float x) {
  return 0.5f * x * (1.0f + erff(x * 0.70710678118654752440f));
}

// ---------------- prologue: levels (chunked Gauss-Seidel), counting sort,
// ---------------- permuted dep lists, consumed flags, barrier reset ----------------
__global__ __launch_bounds__(1024) void k_prologue(
    const int* __restrict__ dep_idx, const int* __restrict__ dep_mask,
    int* __restrict__ meta) {
  __shared__ int lvl[NN];
  __shared__ int cnt[NN];
  __shared__ int pos[NN];
  __shared__ int cons[NN];
  __shared__ int s_changed, s_max;
  const int t = threadIdx.x;
  for (int i = t; i < NN; i += 1024) { lvl[i] = 0; cnt[i] = 0; cons[i] = 0; }
  if (t == 0) s_max = 0;
  __syncthreads();
  // 4 chunks of 1024 nodes in index order; deps < i so levels final per chunk.
  for (int u = 0; u < 4; ++u) {
    const int i = u * 1024 + t;
    const int4 d0 = *(const int4*)&dep_idx[i * MD];
    const int4 d1 = *(const int4*)&dep_idx[i * MD + 4];
    const int4 m0 = *(const int4*)&dep_mask[i * MD];
    const int4 m1 = *(const int4*)&dep_mask[i * MD + 4];
    int my = 0;
    for (;;) {
      if (t == 0) s_changed = 0;
      __syncthreads();
      int m = 0;
      if (m0.x) { int l = lvl[d0.x] + 1; m = m > l ? m : l; }
      if (m0.y) { int l = lvl[d0.y] + 1; m = m > l ? m : l; }
      if (m0.z) { int l = lvl[d0.z] + 1; m = m > l ? m : l; }
      if (m0.w) { int l = lvl[d0.w] + 1; m = m > l ? m : l; }
      if (m1.x) { int l = lvl[d1.x] + 1; m = m > l ? m : l; }
      if (m1.y) { int l = lvl[d1.y] + 1; m = m > l ? m : l; }
      if (m1.z) { int l = lvl[d1.z] + 1; m = m > l ? m : l; }
      if (m1.w) { int l = lvl[d1.w] + 1; m = m > l ? m : l; }
      if (m > my) { my = m; lvl[i] = m; s_changed = 1; }
      __syncthreads();
      if (!s_changed) break;
    }
    if (m0.x) cons[d0.x] = 1;
    if (m0.y) cons[d0.y] = 1;
    if (m0.z) cons[d0.z] = 1;
    if (m0.w) cons[d0.w] = 1;
    if (m1.x) cons[d1.x] = 1;
    if (m1.y) cons[d1.y] = 1;
    if (m1.z) cons[d1.z] = 1;
    if (m1.w) cons[d1.w] = 1;
    __syncthreads();
  }
  for (int i = t; i < NN; i += 1024) { atomicAdd(&cnt[lvl[i]], 1); atomicMax(&s_max, lvl[i]); }
  __syncthreads();
  const int nL = s_max + 1;
  if (t == 0) {
    int off = 0;
    for (int l = 0; l < nL; ++l) { int c = cnt[l]; meta[MI_LO + l] = off; cnt[l] = off; off += c; }
    meta[MI_LO + nL] = off;
    meta[MI_NLEV] = nL;
  }
  __syncthreads();
  for (int i = t; i < NN; i += 1024) pos[i] = atomicAdd(&cnt[lvl[i]], 1);
  __syncthreads();
  for (int i = t; i < NN; i += 1024) {
    const int r = pos[i];
    meta[MI_PERM + r] = i;
    int nd = 0;
    #pragma unroll
    for (int d = 0; d < MD; ++d) {
      if (dep_mask[i * MD + d]) { meta[MI_DPOS + r * MD + nd] = pos[dep_idx[i * MD + d]]; ++nd; }
    }
    for (int d = nd; d < MD; ++d) meta[MI_DPOS + r * MD + d] = 0;
    meta[MI_DCNT + r] = nd;
    ((float*)meta)[MI_INV + r] = nd ? 1.0f / (float)nd : 0.0f;
    meta[MI_CONS + r] = cons[i];
  }
  if (t == 0) meta[MI_ROOTPOS] = pos[NN - 1];
  for (int i = t; i < NW; i += 1024) meta[MI_ARRIVE + i] = 0;
}

// ---------------- preQ = Q @ W1[:, :1024]^T + b1  (fp32 tiled GEMM) ----------------
__global__ __launch_bounds__(256) void k_preq(
    const float* __restrict__ Q, const float* __restrict__ W1,
    const float* __restrict__ b1, float* __restrict__ preQ) {
  __shared__ float As[16][65];
  __shared__ float Bs[16][65];
  const int t = threadIdx.x;
  const int m0 = blockIdx.y * 64, n0 = blockIdx.x * 64;
  const int lm = t >> 2;
  const int lk = (t & 3) << 2;
  const int tm = (t & 15) << 2;
  const int tn = (t >> 4) << 2;
  float acc[4][4] = {};
  for (int k0 = 0; k0 < DM; k0 += 16) {
    __syncthreads();
    float4 a = *(const float4*)&Q[(size_t)(m0 + lm) * DM + k0 + lk];
    As[lk + 0][lm] = a.x; As[lk + 1][lm] = a.y; As[lk + 2][lm] = a.z; As[lk + 3][lm] = a.w;
    float4 b = *(const float4*)&W1[(size_t)(n0 + lm) * 2048 + k0 + lk];
    Bs[lk + 0][lm] = b.x; Bs[lk + 1][lm] = b.y; Bs[lk + 2][lm] = b.z; Bs[lk + 3][lm] = b.w;
    __syncthreads();
    #pragma unroll
    for (int kk = 0; kk < 16; ++kk) {
      float av0 = As[kk][tm], av1 = As[kk][tm + 1], av2 = As[kk][tm + 2], av3 = As[kk][tm + 3];
      float bv0 = Bs[kk][tn], bv1 = Bs[kk][tn + 1], bv2 = Bs[kk][tn + 2], bv3 = Bs[kk][tn + 3];
      acc[0][0] += av0 * bv0; acc[0][1] += av0 * bv1; acc[0][2] += av0 * bv2; acc[0][3] += av0 * bv3;
      acc[1][0] += av1 * bv0; acc[1][1] += av1 * bv1; acc[1][2] += av1 * bv2; acc[1][3] += av1 * bv3;
      acc[2][0] += av2 * bv0; acc[2][1] += av2 * bv1; acc[2][2] += av2 * bv2; acc[2][3] += av2 * bv3;
      acc[3][0] += av3 * bv0; acc[3][1] += av3 * bv1; acc[3][2] += av3 * bv2; acc[3][3] += av3 * bv3;
    }
  }
  #pragma unroll
  for (int i = 0; i < 4; ++i)
    #pragma unroll
    for (int jj = 0; jj < 4; ++jj)
      preQ[(size_t)(m0 + tm + i) * DM + n0 + tn + jj] = acc[i][jj] + b1[n0 + tn + jj];
}

// ---------------- persistent column-sliced dataflow, fence-free barrier ----------------
__global__ __launch_bounds__(256) void k_levels(
    const float* __restrict__ W1, const float* __restrict__ preQ,
    float* __restrict__ hP, float4* __restrict__ gPan, int* __restrict__ meta) {
  const int tid = threadIdx.x;
  const int wb = blockIdx.x;
  const int c0 = wb * NCOL;
  const int wave = tid >> 6, lane = tid & 63;
  const int nL = meta[MI_NLEV];
  const int rootRow = meta[MI_ROOTPOS];
  __shared__ int s_lo[MAXL];
  for (int i = tid; i <= nL; i += 256) s_lo[i] = meta[MI_LO + i];
  // W1c slice (4 rows x 1024) held in registers for the whole kernel:
  // lane's chunk: cols [c0..c0+3], k in {j*256 + lane*4 .. +3}, j=0..3
  float4 wr[NCOL][4];
  #pragma unroll
  for (int cc = 0; cc < NCOL; ++cc)
    #pragma unroll
    for (int j = 0; j < 4; ++j)
      wr[cc][j] = *(const float4*)&W1[(size_t)(c0 + cc) * 2048 + 1024 + (j * 64 + lane) * 4];
  __syncthreads();
  float4* gp = gPan + (size_t)wb * NN;   // block-private g panel
  const float* invA = (const float*)&meta[MI_INV];

  for (int l = 0; l < nL; ++l) {
    const int lo = s_lo[l], hi = s_lo[l + 1];

    // ---- A-phase: thread-per-row, own 4 columns; deps read from OWN panel ----
    for (int r = lo + tid; r < hi; r += 256) {
      if (!meta[MI_CONS + r] && r != rootRow) continue;
      const int node = meta[MI_PERM + r];
      const int nd = meta[MI_DCNT + r];
      const float iv = invA[r];
      const int4 p0 = *(const int4*)&meta[MI_DPOS + r * MD];
      const int4 p1 = *(const int4*)&meta[MI_DPOS + r * MD + 4];
      const int dps[8] = {p0.x, p0.y, p0.z, p0.w, p1.x, p1.y, p1.z, p1.w};
      float sx = 0.f, sy = 0.f, sz = 0.f, sw = 0.f;
      #pragma unroll
      for (int d = 0; d < MD; ++d) {
        float4 v = gp[dps[d]];
        sx += (d < nd) ? v.x : 0.f;
        sy += (d < nd) ? v.y : 0.f;
        sz += (d < nd) ? v.z : 0.f;
        sw += (d < nd) ? v.w : 0.f;
      }
      const float4 pq = *(const float4*)&preQ[(size_t)node * DM + c0];
      float* hrow = &hP[(size_t)r * DM + c0];
      __hip_atomic_store(&hrow[0], gelu_f(pq.x + sx * iv), __ATOMIC_RELAXED, __HIP_MEMORY_SCOPE_AGENT);
      __hip_atomic_store(&hrow[1], gelu_f(pq.y + sy * iv), __ATOMIC_RELAXED, __HIP_MEMORY_SCOPE_AGENT);
      __hip_atomic_store(&hrow[2], gelu_f(pq.z + sz * iv), __ATOMIC_RELAXED, __HIP_MEMORY_SCOPE_AGENT);
      __hip_atomic_store(&hrow[3], gelu_f(pq.w + sw * iv), __ATOMIC_RELAXED, __HIP_MEMORY_SCOPE_AGENT);
    }

    // ---- fence-free all-to-all barrier (h(l) stores are already MALL-coherent;
    // ---- __syncthreads drains vmcnt before s_barrier) ----
    __syncthreads();
    if (tid == 0)
      __hip_atomic_store(&meta[MI_ARRIVE + wb], l + 1, __ATOMIC_RELAXED, __HIP_MEMORY_SCOPE_AGENT);
    if (tid < 64) {
      for (;;) {
        int m = 1 << 30;
        #pragma unroll
        for (int u = 0; u < 4; ++u) {
          int v = __hip_atomic_load(&meta[MI_ARRIVE + tid * 4 + u], __ATOMIC_RELAXED, __HIP_MEMORY_SCOPE_AGENT);
          m = v < m ? v : m;
        }
        #pragma unroll
        for (int off = 1; off < 64; off <<= 1) {
          int o = __shfl_xor(m, off);
          m = o < m ? o : m;
        }
        if (m >= l + 1) break;
        __builtin_amdgcn_s_sleep(1);
      }
    }
    __syncthreads();

    // ---- B-phase: wave-per-row, g[r, own 4 cols] from register-resident W ----
    for (int r = lo + wave; r < hi; r += 4) {
      if (!meta[MI_CONS + r]) continue;
      const float4* h4 = (const float4*)&hP[(size_t)r * DM];
      const float4 hv0 = h4[lane], hv1 = h4[64 + lane], hv2 = h4[128 + lane], hv3 = h4[192 + lane];
      float rr[NCOL];
      #pragma unroll
      for (int cc = 0; cc < NCOL; ++cc) {
        float a = hv0.x * wr[cc][0].x + hv0.y * wr[cc][0].y + hv0.z * wr[cc][0].z + hv0.w * wr[cc][0].w
                + hv1.x * wr[cc][1].x + hv1.y * wr[cc][1].y + hv1.z * wr[cc][1].z + hv1.w * wr[cc][1].w
                + hv2.x * wr[cc][2].x + hv2.y * wr[cc][2].y + hv2.z * wr[cc][2].z + hv2.w * wr[cc][2].w
                + hv3.x * wr[cc][3].x + hv3.y * wr[cc][3].y + hv3.z * wr[cc][3].z + hv3.w * wr[cc][3].w;
        #pragma unroll
        for (int off = 1; off < 64; off <<= 1) a += __shfl_xor(a, off);
        rr[cc] = a;
      }
      if (lane == 0) gp[r] = make_float4(rr[0], rr[1], rr[2], rr[3]);
    }
    __syncthreads();   // own-panel writes visible block-wide for next level's A
  }
}

// ---------------- logits = W2 @ h[root] + b2 ----------------
__global__ __launch_bounds__(256) void k_logits(
    const float* __restrict__ W2, const float* __restrict__ b2,
    const float* __restrict__ hP, const int* __restrict__ meta, float* __restrict__ out) {
  __shared__ float red[256];
  const int t = threadIdx.x;
  const int row = meta[MI_ROOTPOS];
  const int j = t >> 2, kc = t & 3;
  const float* h = hP + (size_t)row * DM;
  const float* wr = W2 + (size_t)j * DM;
  float acc = 0.f;
  for (int k = kc * 256; k < kc * 256 + 256; k += 4) {
    float4 hv = *(const float4*)&h[k];
    float4 wv = *(const float4*)&wr[k];
    acc += hv.x * wv.x + hv.y * wv.y + hv.z * wv.z + hv.w * wv.w;
  }
  red[t] = acc;
  __syncthreads();
  if (kc == 0) out[j] = red[t] + red[t + 1] + red[t + 2] + red[t + 3] + b2[j];
}

extern "C" void kernel_launch(void* const* d_in, const int* in_sizes, int n_in,
                              void* d_out, int out_size, void* d_ws, size_t ws_size,
                              hipStream_t stream) {
  const float* Q        = (const float*)d_in[0];
  const float* W1       = (const float*)d_in[1];
  const float* b1       = (const float*)d_in[2];
  const float* W2       = (const float*)d_in[3];
  const float* b2       = (const float*)d_in[4];
  const int*   dep_idx  = (const int*)d_in[5];
  const int*   dep_mask = (const int*)d_in[6];

  float*  wsf  = (float*)d_ws;
  float*  preQ = wsf;                         // 16 MB
  float*  hP   = wsf + (size_t)NN * DM;       // 16 MB (level-permuted rows, agent-coherent stores)
  float4* gPan = (float4*)(wsf + 2ull * NN * DM); // 16 MB: 256 block-private panels [NN] of float4
  int*    meta = (int*)((char*)d_ws + 3ull * NN * DM * sizeof(float));
  float*  out  = (float*)d_out;

  k_prologue<<<dim3(1), dim3(1024), 0, stream>>>(dep_idx, dep_mask, meta);
  k_preq<<<dim3(DM / 64, NN / 64), dim3(256), 0, stream>>>(Q, W1, b1, preQ);
  k_levels<<<dim3(NW), dim3(256), 0, stream>>>(W1, preQ, hP, gPan, meta);
  k_logits<<<dim3(1), dim3(256), 0, stream>>>(W2, b2, hP, meta, out);
}

// Round 6
// 771.614 us; speedup vs baseline: 11.9118x; 1.7383x over previous
//
#include <hip/hip_runtime.h>

#define NN 4096
#define DM 1024
#define MD 8
#define NW 256          // worker blocks = column slices
#define NCOL 4          // columns per block (NW*NCOL = DM)
#define NT 512          // threads per k_levels block
#define NWAVE (NT / 64)
#define UR 4            // B-phase row unroll per wave
#define MAXL 4097

// meta layout (int offsets within meta region of d_ws)
#define MI_NLEV 0
#define MI_ROOTPOS 1
#define MI_ARRIVE 8     // arrive[NW]
#define MI_LO 1024      // levelOffset[nL+1]
#define MI_NL 6144      // live count per level
#define MI_PERM 10240   // perm[4096] (row -> node)
#define MI_DCNT 14336   // dep count per permuted row
#define MI_INV 18432    // (float) 1/nd per permuted row
#define MI_DPOS 22528   // dpos[4096*8]: permuted dep rows (padded with 0)

__device__ __forceinline__ float gelu_f(float x) {
  return 0.5f * x * (1.0f + erff(x * 0.70710678118654752440f));
}

// ---------------- prologue: levels (chunked Gauss-Seidel), transitive liveness,
// ---------------- (level, live-first) counting sort, dep lists, barrier reset ----------------
__global__ __launch_bounds__(1024) void k_prologue(
    const int* __restrict__ dep_idx, const int* __restrict__ dep_mask,
    int* __restrict__ meta) {
  __shared__ int lvl[NN];
  __shared__ int cnt[2 * NN];
  __shared__ int pos[NN];
  __shared__ int liv[NN];
  __shared__ int s_changed, s_max;
  const int t = threadIdx.x;
  for (int i = t; i < NN; i += 1024) { lvl[i] = 0; pos[i] = 0; liv[i] = (i == NN - 1) ? 1 : 0; }
  for (int i = t; i < 2 * NN; i += 1024) cnt[i] = 0;
  if (t == 0) s_max = 0;
  __syncthreads();
  // forward: 4 chunks of 1024 in index order; deps < i so levels final per chunk.
  for (int u = 0; u < 4; ++u) {
    const int i = u * 1024 + t;
    const int4 d0 = *(const int4*)&dep_idx[i * MD];
    const int4 d1 = *(const int4*)&dep_idx[i * MD + 4];
    const int4 m0 = *(const int4*)&dep_mask[i * MD];
    const int4 m1 = *(const int4*)&dep_mask[i * MD + 4];
    int my = 0;
    for (;;) {
      if (t == 0) s_changed = 0;
      __syncthreads();
      int m = 0;
      if (m0.x) { int l = lvl[d0.x] + 1; m = m > l ? m : l; }
      if (m0.y) { int l = lvl[d0.y] + 1; m = m > l ? m : l; }
      if (m0.z) { int l = lvl[d0.z] + 1; m = m > l ? m : l; }
      if (m0.w) { int l = lvl[d0.w] + 1; m = m > l ? m : l; }
      if (m1.x) { int l = lvl[d1.x] + 1; m = m > l ? m : l; }
      if (m1.y) { int l = lvl[d1.y] + 1; m = m > l ? m : l; }
      if (m1.z) { int l = lvl[d1.z] + 1; m = m > l ? m : l; }
      if (m1.w) { int l = lvl[d1.w] + 1; m = m > l ? m : l; }
      if (m > my) { my = m; lvl[i] = m; s_changed = 1; }
      __syncthreads();
      if (!s_changed) break;
    }
  }
  // backward: transitive liveness from root (chunks in reverse order)
  for (int u = 3; u >= 0; --u) {
    const int i = u * 1024 + t;
    const int4 d0 = *(const int4*)&dep_idx[i * MD];
    const int4 d1 = *(const int4*)&dep_idx[i * MD + 4];
    const int4 m0 = *(const int4*)&dep_mask[i * MD];
    const int4 m1 = *(const int4*)&dep_mask[i * MD + 4];
    for (;;) {
      if (t == 0) s_changed = 0;
      __syncthreads();
      if (liv[i]) {
        if (m0.x && !liv[d0.x]) { liv[d0.x] = 1; s_changed = 1; }
        if (m0.y && !liv[d0.y]) { liv[d0.y] = 1; s_changed = 1; }
        if (m0.z && !liv[d0.z]) { liv[d0.z] = 1; s_changed = 1; }
        if (m0.w && !liv[d0.w]) { liv[d0.w] = 1; s_changed = 1; }
        if (m1.x && !liv[d1.x]) { liv[d1.x] = 1; s_changed = 1; }
        if (m1.y && !liv[d1.y]) { liv[d1.y] = 1; s_changed = 1; }
        if (m1.z && !liv[d1.z]) { liv[d1.z] = 1; s_changed = 1; }
        if (m1.w && !liv[d1.w]) { liv[d1.w] = 1; s_changed = 1; }
      }
      __syncthreads();
      if (!s_changed) break;
    }
  }
  // counting sort by key = 2*level + (dead?1:0)
  for (int i = t; i < NN; i += 1024) {
    atomicAdd(&cnt[2 * lvl[i] + (liv[i] ? 0 : 1)], 1);
    atomicMax(&s_max, lvl[i]);
  }
  __syncthreads();
  const int nL = s_max + 1;
  if (t == 0) {
    int off = 0;
    for (int l = 0; l < nL; ++l) {
      meta[MI_LO + l] = off;
      meta[MI_NL + l] = cnt[2 * l];
      int a = cnt[2 * l], b = cnt[2 * l + 1];
      cnt[2 * l] = off; off += a;
      cnt[2 * l + 1] = off; off += b;
    }
    meta[MI_LO + nL] = off;
    meta[MI_NLEV] = nL;
  }
  __syncthreads();
  for (int i = t; i < NN; i += 1024)
    pos[i] = atomicAdd(&cnt[2 * lvl[i] + (liv[i] ? 0 : 1)], 1);
  __syncthreads();
  for (int i = t; i < NN; i += 1024) {
    const int r = pos[i];
    meta[MI_PERM + r] = i;
    int nd = 0;
    #pragma unroll
    for (int d = 0; d < MD; ++d) {
      if (dep_mask[i * MD + d]) { meta[MI_DPOS + r * MD + nd] = pos[dep_idx[i * MD + d]]; ++nd; }
    }
    for (int d = nd; d < MD; ++d) meta[MI_DPOS + r * MD + d] = 0;
    meta[MI_DCNT + r] = nd;
    ((float*)meta)[MI_INV + r] = nd ? 1.0f / (float)nd : 0.0f;
  }
  if (t == 0) meta[MI_ROOTPOS] = pos[NN - 1];
  for (int i = t; i < NW; i += 1024) meta[MI_ARRIVE + i] = 0;
}

// ---------------- preQ = Q @ W1[:, :1024]^T + b1  (fp32 tiled GEMM) ----------------
__global__ __launch_bounds__(256) void k_preq(
    const float* __restrict__ Q, const float* __restrict__ W1,
    const float* __restrict__ b1, float* __restrict__ preQ) {
  __shared__ float As[16][65];
  __shared__ float Bs[16][65];
  const int t = threadIdx.x;
  const int m0 = blockIdx.y * 64, n0 = blockIdx.x * 64;
  const int lm = t >> 2;
  const int lk = (t & 3) << 2;
  const int tm = (t & 15) << 2;
  const int tn = (t >> 4) << 2;
  float acc[4][4] = {};
  for (int k0 = 0; k0 < DM; k0 += 16) {
    __syncthreads();
    float4 a = *(const float4*)&Q[(size_t)(m0 + lm) * DM + k0 + lk];
    As[lk + 0][lm] = a.x; As[lk + 1][lm] = a.y; As[lk + 2][lm] = a.z; As[lk + 3][lm] = a.w;
    float4 b = *(const float4*)&W1[(size_t)(n0 + lm) * 2048 + k0 + lk];
    Bs[lk + 0][lm] = b.x; Bs[lk + 1][lm] = b.y; Bs[lk + 2][lm] = b.z; Bs[lk + 3][lm] = b.w;
    __syncthreads();
    #pragma unroll
    for (int kk = 0; kk < 16; ++kk) {
      float av0 = As[kk][tm], av1 = As[kk][tm + 1], av2 = As[kk][tm + 2], av3 = As[kk][tm + 3];
      float bv0 = Bs[kk][tn], bv1 = Bs[kk][tn + 1], bv2 = Bs[kk][tn + 2], bv3 = Bs[kk][tn + 3];
      acc[0][0] += av0 * bv0; acc[0][1] += av0 * bv1; acc[0][2] += av0 * bv2; acc[0][3] += av0 * bv3;
      acc[1][0] += av1 * bv0; acc[1][1] += av1 * bv1; acc[1][2] += av1 * bv2; acc[1][3] += av1 * bv3;
      acc[2][0] += av2 * bv0; acc[2][1] += av2 * bv1; acc[2][2] += av2 * bv2; acc[2][3] += av2 * bv3;
      acc[3][0] += av3 * bv0; acc[3][1] += av3 * bv1; acc[3][2] += av3 * bv2; acc[3][3] += av3 * bv3;
    }
  }
  #pragma unroll
  for (int i = 0; i < 4; ++i)
    #pragma unroll
    for (int jj = 0; jj < 4; ++jj)
      preQ[(size_t)(m0 + tm + i) * DM + n0 + tn + jj] = acc[i][jj] + b1[n0 + tn + jj];
}

// ---------------- persistent column-sliced dataflow ----------------
__global__ __launch_bounds__(NT) void k_levels(
    const float* __restrict__ W1, const float* __restrict__ preQ,
    float* __restrict__ hP, float4* __restrict__ gPan, int* __restrict__ meta) {
  const int tid = threadIdx.x;
  const int wb = blockIdx.x;
  const int c0 = wb * NCOL;
  const int wave = tid >> 6, lane = tid & 63;
  const int nL = meta[MI_NLEV];
  __shared__ int s_lo[MAXL];
  __shared__ int s_nl[MAXL];
  __shared__ float4 preLDS[NT];
  for (int i = tid; i <= nL; i += NT) s_lo[i] = meta[MI_LO + i];
  for (int i = tid; i < nL; i += NT) s_nl[i] = meta[MI_NL + i];
  // W1c slice (4 rows x 1024) in registers; lane k-chunk: (j*64+lane)*4
  float4 wr[NCOL][4];
  #pragma unroll
  for (int cc = 0; cc < NCOL; ++cc)
    #pragma unroll
    for (int j = 0; j < 4; ++j)
      wr[cc][j] = *(const float4*)&W1[(size_t)(c0 + cc) * 2048 + 1024 + (j * 64 + lane) * 4];
  __syncthreads();
  float4* gp = gPan + (size_t)wb * NN;   // block-private g panel
  const float* invA = (const float*)&meta[MI_INV];

  for (int l = 0; l < nL; ++l) {
    const int lo = s_lo[l];
    const int nA = s_nl[l];   // live rows (live-first ordering)

    // ---- A-phase: thread-per-row, own 4 columns ----
    for (int r = lo + tid; r < lo + nA; r += NT) {
      const int node = meta[MI_PERM + r];
      const int nd = meta[MI_DCNT + r];
      const float iv = invA[r];
      const int4 p0 = *(const int4*)&meta[MI_DPOS + r * MD];
      const int4 p1 = *(const int4*)&meta[MI_DPOS + r * MD + 4];
      const int dps[8] = {p0.x, p0.y, p0.z, p0.w, p1.x, p1.y, p1.z, p1.w};
      float sx = 0.f, sy = 0.f, sz = 0.f, sw = 0.f;
      #pragma unroll
      for (int d = 0; d < MD; ++d) {
        float4 v = gp[dps[d]];
        sx += (d < nd) ? v.x : 0.f;
        sy += (d < nd) ? v.y : 0.f;
        sz += (d < nd) ? v.z : 0.f;
        sw += (d < nd) ? v.w : 0.f;
      }
      const float4 pq = (l > 0 && r == lo + tid) ? preLDS[tid]
                                                 : *(const float4*)&preQ[(size_t)node * DM + c0];
      float4 hv4;
      hv4.x = gelu_f(pq.x + sx * iv);
      hv4.y = gelu_f(pq.y + sy * iv);
      hv4.z = gelu_f(pq.z + sz * iv);
      hv4.w = gelu_f(pq.w + sw * iv);
      // 16B as two 8B agent-coherent write-throughs (MALL-visible, compiler-tracked)
      unsigned long long u0, u1;
      __builtin_memcpy(&u0, &hv4.x, 8);
      __builtin_memcpy(&u1, &hv4.z, 8);
      unsigned long long* hrow = (unsigned long long*)&hP[(size_t)r * DM + c0];
      __hip_atomic_store(&hrow[0], u0, __ATOMIC_RELAXED, __HIP_MEMORY_SCOPE_AGENT);
      __hip_atomic_store(&hrow[1], u1, __ATOMIC_RELAXED, __HIP_MEMORY_SCOPE_AGENT);
    }
    __syncthreads();   // drains vmcnt before s_barrier -> h stores MALL-visible
    if (tid == 0)
      __hip_atomic_store(&meta[MI_ARRIVE + wb], l + 1, __ATOMIC_RELAXED, __HIP_MEMORY_SCOPE_AGENT);
    // prefetch next level's preQ into LDS while the barrier resolves
    if (l + 1 < nL && tid < s_nl[l + 1]) {
      const int node2 = meta[MI_PERM + s_lo[l + 1] + tid];
      preLDS[tid] = *(const float4*)&preQ[(size_t)node2 * DM + c0];
    }
    if (tid < 64) {
      for (;;) {
        int m = 1 << 30;
        #pragma unroll
        for (int u = 0; u < 4; ++u) {
          int v = __hip_atomic_load(&meta[MI_ARRIVE + tid * 4 + u], __ATOMIC_RELAXED, __HIP_MEMORY_SCOPE_AGENT);
          m = v < m ? v : m;
        }
        #pragma unroll
        for (int off = 1; off < 64; off <<= 1) {
          int o = __shfl_xor(m, off);
          m = o < m ? o : m;
        }
        if (m >= l + 1) break;
        __builtin_amdgcn_s_sleep(1);
      }
    }
    __syncthreads();

    // ---- B-phase: 4-row unrolled wave-per-row, W in registers ----
    for (int base = wave * UR; base < nA; base += NWAVE * UR) {
      const int cnt = nA - base;            // rows remaining (>=1)
      float4 hv[UR][4];
      #pragma unroll
      for (int u = 0; u < UR; ++u) {
        const int r = lo + base + ((u < cnt) ? u : 0);
        const float4* h4 = (const float4*)&hP[(size_t)r * DM];
        hv[u][0] = h4[lane];       hv[u][1] = h4[64 + lane];
        hv[u][2] = h4[128 + lane]; hv[u][3] = h4[192 + lane];
      }
      float rr[UR][NCOL];
      #pragma unroll
      for (int u = 0; u < UR; ++u)
        #pragma unroll
        for (int cc = 0; cc < NCOL; ++cc) {
          float a = hv[u][0].x * wr[cc][0].x + hv[u][0].y * wr[cc][0].y + hv[u][0].z * wr[cc][0].z + hv[u][0].w * wr[cc][0].w
                  + hv[u][1].x * wr[cc][1].x + hv[u][1].y * wr[cc][1].y + hv[u][1].z * wr[cc][1].z + hv[u][1].w * wr[cc][1].w
                  + hv[u][2].x * wr[cc][2].x + hv[u][2].y * wr[cc][2].y + hv[u][2].z * wr[cc][2].z + hv[u][2].w * wr[cc][2].w
                  + hv[u][3].x * wr[cc][3].x + hv[u][3].y * wr[cc][3].y + hv[u][3].z * wr[cc][3].z + hv[u][3].w * wr[cc][3].w;
          rr[u][cc] = a;
        }
      #pragma unroll
      for (int off = 1; off < 64; off <<= 1)
        #pragma unroll
        for (int u = 0; u < UR; ++u)
          #pragma unroll
          for (int cc = 0; cc < NCOL; ++cc)
            rr[u][cc] += __shfl_xor(rr[u][cc], off);
      if (lane == 0) {
        #pragma unroll
        for (int u = 0; u < UR; ++u)
          if (u < cnt) gp[lo + base + u] = make_float4(rr[u][0], rr[u][1], rr[u][2], rr[u][3]);
      }
    }
    __syncthreads();   // own-panel writes visible block-wide for next level's A
  }
}

// ---------------- logits = W2 @ h[root] + b2 ----------------
__global__ __launch_bounds__(256) void k_logits(
    const float* __restrict__ W2, const float* __restrict__ b2,
    const float* __restrict__ hP, const int* __restrict__ meta, float* __restrict__ out) {
  __shared__ float red[256];
  const int t = threadIdx.x;
  const int row = meta[MI_ROOTPOS];
  const int j = t >> 2, kc = t & 3;
  const float* h = hP + (size_t)row * DM;
  const float* wr = W2 + (size_t)j * DM;
  float acc = 0.f;
  for (int k = kc * 256; k < kc * 256 + 256; k += 4) {
    float4 hv = *(const float4*)&h[k];
    float4 wv = *(const float4*)&wr[k];
    acc += hv.x * wv.x + hv.y * wv.y + hv.z * wv.z + hv.w * wv.w;
  }
  red[t] = acc;
  __syncthreads();
  if (kc == 0) out[j] = red[t] + red[t + 1] + red[t + 2] + red[t + 3] + b2[j];
}

extern "C" void kernel_launch(void* const* d_in, const int* in_sizes, int n_in,
                              void* d_out, int out_size, void* d_ws, size_t ws_size,
                              hipStream_t stream) {
  const float* Q        = (const float*)d_in[0];
  const float* W1       = (const float*)d_in[1];
  const float* b1       = (const float*)d_in[2];
  const float* W2       = (const float*)d_in[3];
  const float* b2       = (const float*)d_in[4];
  const int*   dep_idx  = (const int*)d_in[5];
  const int*   dep_mask = (const int*)d_in[6];

  float*  wsf  = (float*)d_ws;
  float*  preQ = wsf;                         // 16 MB
  float*  hP   = wsf + (size_t)NN * DM;       // 16 MB (level-permuted rows, agent-coherent stores)
  float4* gPan = (float4*)(wsf + 2ull * NN * DM); // 16 MB: 256 block-private panels [NN] of float4
  int*    meta = (int*)((char*)d_ws + 3ull * NN * DM * sizeof(float));
  float*  out  = (float*)d_out;

  k_prologue<<<dim3(1), dim3(1024), 0, stream>>>(dep_idx, dep_mask, meta);
  k_preq<<<dim3(DM / 64, NN / 64), dim3(256), 0, stream>>>(Q, W1, b1, preQ);
  k_levels<<<dim3(NW), dim3(NT), 0, stream>>>(W1, preQ, hP, gPan, meta);
  k_logits<<<dim3(1), dim3(256), 0, stream>>>(W2, b2, hP, meta, out);
}

// Round 7
// 557.095 us; speedup vs baseline: 16.4986x; 1.3851x over previous
//
#include <hip/hip_runtime.h>

#define NN 4096
#define DM 1024
#define MD 8
#define NW 256          // worker blocks = column slices
#define NCOL 4          // columns per block (NW*NCOL = DM)
#define NT 512          // threads per k_levels block
#define NWAVE (NT / 64)
#define UR 4            // B-phase row unroll per wave
#define MAXL 4097

// meta layout (int offsets within meta region of d_ws)
#define MI_NLEV 0
#define MI_ROOTPOS 1
#define MI_ARRIVE 8     // arrive[NW]
#define MI_LO 1024      // levelOffset[nL+1]
#define MI_NL 6144      // live count per level
#define MI_PERM 10240   // perm[4096] (row -> node)
#define MI_DCNT 14336   // dep count per permuted row
#define MI_INV 18432    // (float) 1/nd per permuted row
#define MI_DPOS 22528   // dpos[4096*8]: permuted dep rows (padded with 0)

typedef __attribute__((ext_vector_type(8))) short bf16x8;
typedef __attribute__((ext_vector_type(8))) unsigned short ushort8;
typedef __attribute__((ext_vector_type(4))) float f32x4;

__device__ __forceinline__ float gelu_f(float x) {
  return 0.5f * x * (1.0f + erff(x * 0.70710678118654752440f));
}
__device__ __forceinline__ unsigned short f2bf(float x) {   // RTNE
  unsigned int u = __builtin_bit_cast(unsigned int, x);
  u += 0x7FFFu + ((u >> 16) & 1u);
  return (unsigned short)(u >> 16);
}
__device__ __forceinline__ float bf2f(unsigned short v) {
  return __builtin_bit_cast(float, (unsigned int)v << 16);
}

// ---------------- prologue: levels (chunked Gauss-Seidel), transitive liveness,
// ---------------- (level, live-first) counting sort, dep lists, barrier reset ----------------
__global__ __launch_bounds__(1024) void k_prologue(
    const int* __restrict__ dep_idx, const int* __restrict__ dep_mask,
    int* __restrict__ meta) {
  __shared__ int lvl[NN];
  __shared__ int cnt[2 * NN];
  __shared__ int pos[NN];
  __shared__ int liv[NN];
  __shared__ int s_changed, s_max;
  const int t = threadIdx.x;
  for (int i = t; i < NN; i += 1024) { lvl[i] = 0; pos[i] = 0; liv[i] = (i == NN - 1) ? 1 : 0; }
  for (int i = t; i < 2 * NN; i += 1024) cnt[i] = 0;
  if (t == 0) s_max = 0;
  __syncthreads();
  // forward: 4 chunks of 1024 in index order; deps < i so levels final per chunk.
  for (int u = 0; u < 4; ++u) {
    const int i = u * 1024 + t;
    const int4 d0 = *(const int4*)&dep_idx[i * MD];
    const int4 d1 = *(const int4*)&dep_idx[i * MD + 4];
    const int4 m0 = *(const int4*)&dep_mask[i * MD];
    const int4 m1 = *(const int4*)&dep_mask[i * MD + 4];
    int my = 0;
    for (;;) {
      if (t == 0) s_changed = 0;
      __syncthreads();
      int m = 0;
      if (m0.x) { int l = lvl[d0.x] + 1; m = m > l ? m : l; }
      if (m0.y) { int l = lvl[d0.y] + 1; m = m > l ? m : l; }
      if (m0.z) { int l = lvl[d0.z] + 1; m = m > l ? m : l; }
      if (m0.w) { int l = lvl[d0.w] + 1; m = m > l ? m : l; }
      if (m1.x) { int l = lvl[d1.x] + 1; m = m > l ? m : l; }
      if (m1.y) { int l = lvl[d1.y] + 1; m = m > l ? m : l; }
      if (m1.z) { int l = lvl[d1.z] + 1; m = m > l ? m : l; }
      if (m1.w) { int l = lvl[d1.w] + 1; m = m > l ? m : l; }
      if (m > my) { my = m; lvl[i] = m; s_changed = 1; }
      __syncthreads();
      if (!s_changed) break;
    }
  }
  // backward: transitive liveness from root (chunks in reverse order)
  for (int u = 3; u >= 0; --u) {
    const int i = u * 1024 + t;
    const int4 d0 = *(const int4*)&dep_idx[i * MD];
    const int4 d1 = *(const int4*)&dep_idx[i * MD + 4];
    const int4 m0 = *(const int4*)&dep_mask[i * MD];
    const int4 m1 = *(const int4*)&dep_mask[i * MD + 4];
    for (;;) {
      if (t == 0) s_changed = 0;
      __syncthreads();
      if (liv[i]) {
        if (m0.x && !liv[d0.x]) { liv[d0.x] = 1; s_changed = 1; }
        if (m0.y && !liv[d0.y]) { liv[d0.y] = 1; s_changed = 1; }
        if (m0.z && !liv[d0.z]) { liv[d0.z] = 1; s_changed = 1; }
        if (m0.w && !liv[d0.w]) { liv[d0.w] = 1; s_changed = 1; }
        if (m1.x && !liv[d1.x]) { liv[d1.x] = 1; s_changed = 1; }
        if (m1.y && !liv[d1.y]) { liv[d1.y] = 1; s_changed = 1; }
        if (m1.z && !liv[d1.z]) { liv[d1.z] = 1; s_changed = 1; }
        if (m1.w && !liv[d1.w]) { liv[d1.w] = 1; s_changed = 1; }
      }
      __syncthreads();
      if (!s_changed) break;
    }
  }
  // counting sort by key = 2*level + (dead?1:0)
  for (int i = t; i < NN; i += 1024) {
    atomicAdd(&cnt[2 * lvl[i] + (liv[i] ? 0 : 1)], 1);
    atomicMax(&s_max, lvl[i]);
  }
  __syncthreads();
  const int nL = s_max + 1;
  if (t == 0) {
    int off = 0;
    for (int l = 0; l < nL; ++l) {
      meta[MI_LO + l] = off;
      meta[MI_NL + l] = cnt[2 * l];
      int a = cnt[2 * l], b = cnt[2 * l + 1];
      cnt[2 * l] = off; off += a;
      cnt[2 * l + 1] = off; off += b;
    }
    meta[MI_LO + nL] = off;
    meta[MI_NLEV] = nL;
  }
  __syncthreads();
  for (int i = t; i < NN; i += 1024)
    pos[i] = atomicAdd(&cnt[2 * lvl[i] + (liv[i] ? 0 : 1)], 1);
  __syncthreads();
  for (int i = t; i < NN; i += 1024) {
    const int r = pos[i];
    meta[MI_PERM + r] = i;
    int nd = 0;
    #pragma unroll
    for (int d = 0; d < MD; ++d) {
      if (dep_mask[i * MD + d]) { meta[MI_DPOS + r * MD + nd] = pos[dep_idx[i * MD + d]]; ++nd; }
    }
    for (int d = nd; d < MD; ++d) meta[MI_DPOS + r * MD + d] = 0;
    meta[MI_DCNT + r] = nd;
    ((float*)meta)[MI_INV + r] = nd ? 1.0f / (float)nd : 0.0f;
  }
  if (t == 0) meta[MI_ROOTPOS] = pos[NN - 1];
  for (int i = t; i < NW; i += 1024) meta[MI_ARRIVE + i] = 0;
}

// ---------------- Q -> bf16 (RTNE), 8 elems/thread ----------------
__global__ __launch_bounds__(256) void k_cvtq(
    const float* __restrict__ Q, unsigned short* __restrict__ Qb) {
  const size_t i = ((size_t)blockIdx.x * 256 + threadIdx.x) * 8;
  float4 a = *(const float4*)&Q[i];
  float4 b = *(const float4*)&Q[i + 4];
  ushort8 o;
  o[0] = f2bf(a.x); o[1] = f2bf(a.y); o[2] = f2bf(a.z); o[3] = f2bf(a.w);
  o[4] = f2bf(b.x); o[5] = f2bf(b.y); o[6] = f2bf(b.z); o[7] = f2bf(b.w);
  *(ushort8*)&Qb[i] = o;
}

// ---------------- preQ = Qb @ bf16(W1[:, :1024])^T + b1  (MFMA bf16) ----------------
__global__ __launch_bounds__(256) void k_preq(
    const unsigned short* __restrict__ Qb, const float* __restrict__ W1,
    const float* __restrict__ b1, float* __restrict__ preQ) {
  const int t = threadIdx.x;
  const int wave = t >> 6, lane = t & 63;
  const int wm = wave >> 1, wn = wave & 1;
  const int m0 = blockIdx.y * 128 + wm * 64;
  const int n0 = blockIdx.x * 128 + wn * 64;
  const int lrow = lane & 15;           // A/B row within 16
  const int klo = (lane >> 4) * 8;      // k sub-chunk
  f32x4 acc[4][4] = {};
  for (int k0 = 0; k0 < DM; k0 += 32) {
    bf16x8 af[4];
    #pragma unroll
    for (int f = 0; f < 4; ++f)
      af[f] = *(const bf16x8*)&Qb[(size_t)(m0 + f * 16 + lrow) * DM + k0 + klo];
    bf16x8 bfr[4];
    #pragma unroll
    for (int g = 0; g < 4; ++g) {
      const float* wsrc = &W1[(size_t)(n0 + g * 16 + lrow) * 2048 + k0 + klo];
      float4 w0 = *(const float4*)&wsrc[0];
      float4 w1 = *(const float4*)&wsrc[4];
      bf16x8 bb;
      bb[0] = (short)f2bf(w0.x); bb[1] = (short)f2bf(w0.y);
      bb[2] = (short)f2bf(w0.z); bb[3] = (short)f2bf(w0.w);
      bb[4] = (short)f2bf(w1.x); bb[5] = (short)f2bf(w1.y);
      bb[6] = (short)f2bf(w1.z); bb[7] = (short)f2bf(w1.w);
      bfr[g] = bb;
    }
    #pragma unroll
    for (int f = 0; f < 4; ++f)
      #pragma unroll
      for (int g = 0; g < 4; ++g)
        acc[f][g] = __builtin_amdgcn_mfma_f32_16x16x32_bf16(af[f], bfr[g], acc[f][g], 0, 0, 0);
  }
  float b1v[4];
  #pragma unroll
  for (int g = 0; g < 4; ++g) b1v[g] = b1[n0 + g * 16 + lrow];
  const int mrow = (lane >> 4) * 4;
  #pragma unroll
  for (int f = 0; f < 4; ++f)
    #pragma unroll
    for (int g = 0; g < 4; ++g) {
      const int n = n0 + g * 16 + lrow;
      #pragma unroll
      for (int r = 0; r < 4; ++r)
        preQ[(size_t)(m0 + f * 16 + mrow + r) * DM + n] = acc[f][g][r] + b1v[g];
    }
}

// ---------------- persistent column-sliced dataflow (bf16 h) ----------------
__global__ __launch_bounds__(NT) void k_levels(
    const float* __restrict__ W1, const float* __restrict__ preQ,
    unsigned short* __restrict__ hPb, float4* __restrict__ gPan, int* __restrict__ meta) {
  const int tid = threadIdx.x;
  const int wb = blockIdx.x;
  const int c0 = wb * NCOL;
  const int wave = tid >> 6, lane = tid & 63;
  const int nL = meta[MI_NLEV];
  __shared__ int s_lo[MAXL];
  __shared__ int s_nl[MAXL];
  __shared__ float4 preLDS[NT];
  for (int i = tid; i <= nL; i += NT) s_lo[i] = meta[MI_LO + i];
  for (int i = tid; i < nL; i += NT) s_nl[i] = meta[MI_NL + i];
  __syncthreads();
  float4* gp = gPan + (size_t)wb * NN;   // block-private g panel (fp32)
  const float* invA = (const float*)&meta[MI_INV];

  for (int l = 0; l < nL; ++l) {
    const int lo = s_lo[l];
    const int nA = s_nl[l];   // live rows (live-first ordering)

    // ---- A-phase: thread-per-row, own 4 columns; pack to bf16, 8B agent store ----
    for (int r = lo + tid; r < lo + nA; r += NT) {
      const int node = meta[MI_PERM + r];
      const int nd = meta[MI_DCNT + r];
      const float iv = invA[r];
      const int4 p0 = *(const int4*)&meta[MI_DPOS + r * MD];
      const int4 p1 = *(const int4*)&meta[MI_DPOS + r * MD + 4];
      const int dps[8] = {p0.x, p0.y, p0.z, p0.w, p1.x, p1.y, p1.z, p1.w};
      float sx = 0.f, sy = 0.f, sz = 0.f, sw = 0.f;
      #pragma unroll
      for (int d = 0; d < MD; ++d) {
        float4 v = gp[dps[d]];
        sx += (d < nd) ? v.x : 0.f;
        sy += (d < nd) ? v.y : 0.f;
        sz += (d < nd) ? v.z : 0.f;
        sw += (d < nd) ? v.w : 0.f;
      }
      const float4 pq = (l > 0 && r == lo + tid) ? preLDS[tid]
                                                 : *(const float4*)&preQ[(size_t)node * DM + c0];
      const unsigned short h0 = f2bf(gelu_f(pq.x + sx * iv));
      const unsigned short h1 = f2bf(gelu_f(pq.y + sy * iv));
      const unsigned short h2 = f2bf(gelu_f(pq.z + sz * iv));
      const unsigned short h3 = f2bf(gelu_f(pq.w + sw * iv));
      const unsigned long long u = (unsigned long long)h0 | ((unsigned long long)h1 << 16)
                                 | ((unsigned long long)h2 << 32) | ((unsigned long long)h3 << 48);
      __hip_atomic_store((unsigned long long*)&hPb[(size_t)r * DM + c0], u,
                         __ATOMIC_RELAXED, __HIP_MEMORY_SCOPE_AGENT);
    }
    __syncthreads();   // drains vmcnt before s_barrier -> h stores MALL-visible
    if (tid == 0)
      __hip_atomic_store(&meta[MI_ARRIVE + wb], l + 1, __ATOMIC_RELAXED, __HIP_MEMORY_SCOPE_AGENT);
    // prefetch next level's preQ into LDS while the barrier resolves
    if (l + 1 < nL && tid < s_nl[l + 1]) {
      const int node2 = meta[MI_PERM + s_lo[l + 1] + tid];
      preLDS[tid] = *(const float4*)&preQ[(size_t)node2 * DM + c0];
    }
    if (tid < 64) {
      for (;;) {
        int m = 1 << 30;
        #pragma unroll
        for (int u = 0; u < 4; ++u) {
          int v = __hip_atomic_load(&meta[MI_ARRIVE + tid * 4 + u], __ATOMIC_RELAXED, __HIP_MEMORY_SCOPE_AGENT);
          m = v < m ? v : m;
        }
        #pragma unroll
        for (int off = 1; off < 64; off <<= 1) {
          int o = __shfl_xor(m, off);
          m = o < m ? o : m;
        }
        if (m >= l + 1) break;
        __builtin_amdgcn_s_sleep(1);
      }
    }
    __syncthreads();

    // ---- B-phase: 4-row unrolled wave-per-row; h bf16 (2 x dwordx4/lane) ----
    for (int base = wave * UR; base < nA; base += NWAVE * UR) {
      const int cnt = nA - base;            // rows remaining (>=1)
      ushort8 hv[UR][2];
      #pragma unroll
      for (int u = 0; u < UR; ++u) {
        const int r = lo + base + ((u < cnt) ? u : 0);
        const ushort8* h8 = (const ushort8*)&hPb[(size_t)r * DM];
        hv[u][0] = h8[lane * 2];
        hv[u][1] = h8[lane * 2 + 1];
      }
      float rr[UR][NCOL];
      #pragma unroll
      for (int cc = 0; cc < NCOL; ++cc) {
        const float* wsrc = &W1[(size_t)(c0 + cc) * 2048 + 1024 + lane * 16];
        const float4 w0 = *(const float4*)&wsrc[0];
        const float4 w1 = *(const float4*)&wsrc[4];
        const float4 w2 = *(const float4*)&wsrc[8];
        const float4 w3 = *(const float4*)&wsrc[12];
        #pragma unroll
        for (int u = 0; u < UR; ++u) {
          float a = bf2f(hv[u][0][0]) * w0.x + bf2f(hv[u][0][1]) * w0.y
                  + bf2f(hv[u][0][2]) * w0.z + bf2f(hv[u][0][3]) * w0.w
                  + bf2f(hv[u][0][4]) * w1.x + bf2f(hv[u][0][5]) * w1.y
                  + bf2f(hv[u][0][6]) * w1.z + bf2f(hv[u][0][7]) * w1.w
                  + bf2f(hv[u][1][0]) * w2.x + bf2f(hv[u][1][1]) * w2.y
                  + bf2f(hv[u][1][2]) * w2.z + bf2f(hv[u][1][3]) * w2.w
                  + bf2f(hv[u][1][4]) * w3.x + bf2f(hv[u][1][5]) * w3.y
                  + bf2f(hv[u][1][6]) * w3.z + bf2f(hv[u][1][7]) * w3.w;
          rr[u][cc] = a;
        }
      }
      #pragma unroll
      for (int off = 1; off < 64; off <<= 1)
        #pragma unroll
        for (int u = 0; u < UR; ++u)
          #pragma unroll
          for (int cc = 0; cc < NCOL; ++cc)
            rr[u][cc] += __shfl_xor(rr[u][cc], off);
      if (lane == 0) {
        #pragma unroll
        for (int u = 0; u < UR; ++u)
          if (u < cnt) gp[lo + base + u] = make_float4(rr[u][0], rr[u][1], rr[u][2], rr[u][3]);
      }
    }
    __syncthreads();   // own-panel writes visible block-wide for next level's A
  }
}

// ---------------- logits = W2 @ h[root] + b2 ----------------
__global__ __launch_bounds__(256) void k_logits(
    const float* __restrict__ W2, const float* __restrict__ b2,
    const unsigned short* __restrict__ hPb, const int* __restrict__ meta,
    float* __restrict__ out) {
  __shared__ float red[256];
  const int t = threadIdx.x;
  const int row = meta[MI_ROOTPOS];
  const int j = t >> 2, kc = t & 3;
  const ushort8* h8 = (const ushort8*)&hPb[(size_t)row * DM];
  const float* wr = W2 + (size_t)j * DM;
  float acc = 0.f;
  for (int k = kc * 256; k < kc * 256 + 256; k += 8) {
    ushort8 hv = h8[k >> 3];
    float4 wa = *(const float4*)&wr[k];
    float4 wb = *(const float4*)&wr[k + 4];
    acc += bf2f(hv[0]) * wa.x + bf2f(hv[1]) * wa.y + bf2f(hv[2]) * wa.z + bf2f(hv[3]) * wa.w
         + bf2f(hv[4]) * wb.x + bf2f(hv[5]) * wb.y + bf2f(hv[6]) * wb.z + bf2f(hv[7]) * wb.w;
  }
  red[t] = acc;
  __syncthreads();
  if (kc == 0) out[j] = red[t] + red[t + 1] + red[t + 2] + red[t + 3] + b2[j];
}

extern "C" void kernel_launch(void* const* d_in, const int* in_sizes, int n_in,
                              void* d_out, int out_size, void* d_ws, size_t ws_size,
                              hipStream_t stream) {
  const float* Q        = (const float*)d_in[0];
  const float* W1       = (const float*)d_in[1];
  const float* b1       = (const float*)d_in[2];
  const float* W2       = (const float*)d_in[3];
  const float* b2       = (const float*)d_in[4];
  const int*   dep_idx  = (const int*)d_in[5];
  const int*   dep_mask = (const int*)d_in[6];

  char* ws = (char*)d_ws;
  float*          preQ = (float*)ws;                              // [0, 16MB)
  unsigned short* hPb  = (unsigned short*)(ws + (16ull << 20));   // [16, 24) bf16 h
  unsigned short* Qb   = (unsigned short*)(ws + (24ull << 20));   // [24, 32) bf16 Q
  float4*         gPan = (float4*)(ws + (32ull << 20));           // [32, 48) block-private g
  int*            meta = (int*)(ws + (48ull << 20));
  float*          out  = (float*)d_out;

  k_prologue<<<dim3(1), dim3(1024), 0, stream>>>(dep_idx, dep_mask, meta);
  k_cvtq<<<dim3((NN * DM) / (256 * 8)), dim3(256), 0, stream>>>(Q, Qb);
  k_preq<<<dim3(DM / 128, NN / 128), dim3(256), 0, stream>>>(Qb, W1, b1, preQ);
  k_levels<<<dim3(NW), dim3(NT), 0, stream>>>(W1, preQ, hPb, gPan, meta);
  k_logits<<<dim3(1), dim3(256), 0, stream>>>(W2, b2, hPb, meta, out);
}

// Round 8
// 556.388 us; speedup vs baseline: 16.5195x; 1.0013x over previous
//
#include <hip/hip_runtime.h>

#define NN 4096
#define DM 1024
#define MD 8
#define NW 256          // worker blocks = column slices
#define NCOL 4          // columns per block (NW*NCOL = DM)
#define NT 512          // threads per k_levels block
#define NWAVE (NT / 64)
#define UR 4            // B-phase row unroll per wave
#define MAXL 4097

// meta layout (int offsets within meta region of d_ws)
#define MI_NLEV 0
#define MI_ROOTPOS 1
#define MI_ARRIVE 8     // arrive[NW]
#define MI_LO 1024      // levelOffset[nL+1]
#define MI_NL 6144      // live count per level
#define MI_PERM 10240   // perm[4096] (row -> node)
#define MI_DCNT 14336   // dep count per permuted row
#define MI_INV 18432    // (float) 1/nd per permuted row
#define MI_DPOS 22528   // dpos[4096*8]: permuted dep rows (padded with 0)

typedef __attribute__((ext_vector_type(8))) short bf16x8;
typedef __attribute__((ext_vector_type(8))) unsigned short ushort8;
typedef __attribute__((ext_vector_type(4))) float f32x4;

__device__ __forceinline__ float gelu_f(float x) {
  return 0.5f * x * (1.0f + erff(x * 0.70710678118654752440f));
}
__device__ __forceinline__ unsigned short f2bf(float x) {   // RTNE
  unsigned int u = __builtin_bit_cast(unsigned int, x);
  u += 0x7FFFu + ((u >> 16) & 1u);
  return (unsigned short)(u >> 16);
}
__device__ __forceinline__ float bf2f(unsigned short v) {
  return __builtin_bit_cast(float, (unsigned int)v << 16);
}

// ---------------- fused: block 0 = graph prologue (single-wave LDS dataflow);
// ---------------- blocks 1..256 = Q -> bf16 conversion (grid-stride) ----------------
__global__ __launch_bounds__(1024) void k_pro(
    const float* __restrict__ Q, const int* __restrict__ dep_idx,
    const int* __restrict__ dep_mask, int* __restrict__ meta,
    unsigned short* __restrict__ Qb) {
  __shared__ unsigned short deps[NN][MD];  // 64KB, dep+1 (0 = none)
  __shared__ unsigned short lvl[NN];       // 8KB
  __shared__ unsigned short liv[NN];       // 8KB
  __shared__ int cnt[2 * NN];              // 32KB
  __shared__ int pos[NN];                  // 16KB   (total 128KB <= 160KB)
  __shared__ int s_max;
  const int t = threadIdx.x;

  if (blockIdx.x != 0) {
    // ---- cvtq: 8 floats/thread, grid-stride ----
    const size_t total = (size_t)NN * DM / 8;
    for (size_t c = (size_t)(blockIdx.x - 1) * 1024 + t; c < total; c += 256 * 1024) {
      const size_t i = c * 8;
      float4 a = *(const float4*)&Q[i];
      float4 b = *(const float4*)&Q[i + 4];
      ushort8 o;
      o[0] = f2bf(a.x); o[1] = f2bf(a.y); o[2] = f2bf(a.z); o[3] = f2bf(a.w);
      o[4] = f2bf(b.x); o[5] = f2bf(b.y); o[6] = f2bf(b.z); o[7] = f2bf(b.w);
      *(ushort8*)&Qb[i] = o;
    }
    return;
  }

  // ---- stage deps into LDS (dep+1 encoding), init ----
  for (int i = t; i < NN; i += 1024) {
    const int4 d0 = *(const int4*)&dep_idx[i * MD];
    const int4 d1 = *(const int4*)&dep_idx[i * MD + 4];
    const int4 m0 = *(const int4*)&dep_mask[i * MD];
    const int4 m1 = *(const int4*)&dep_mask[i * MD + 4];
    deps[i][0] = m0.x ? (unsigned short)(d0.x + 1) : 0;
    deps[i][1] = m0.y ? (unsigned short)(d0.y + 1) : 0;
    deps[i][2] = m0.z ? (unsigned short)(d0.z + 1) : 0;
    deps[i][3] = m0.w ? (unsigned short)(d0.w + 1) : 0;
    deps[i][4] = m1.x ? (unsigned short)(d1.x + 1) : 0;
    deps[i][5] = m1.y ? (unsigned short)(d1.y + 1) : 0;
    deps[i][6] = m1.z ? (unsigned short)(d1.z + 1) : 0;
    deps[i][7] = m1.w ? (unsigned short)(d1.w + 1) : 0;
    lvl[i] = 0;
    liv[i] = (i == NN - 1) ? 1 : 0;
  }
  for (int i = t; i < 2 * NN; i += 1024) cnt[i] = 0;
  if (t == 0) s_max = 0;
  __syncthreads();

  // ---- forward longest-path levels: single wave, 64 sequential groups ----
  if (t < 64) {
    for (int grp = 0; grp < 64; ++grp) {
      const int i = grp * 64 + t;
      const ushort8 dr = *(const ushort8*)&deps[i][0];
      int lvprev = -1;
      for (;;) {
        int m = 0;
        #pragma unroll
        for (int k = 0; k < MD; ++k) {
          const int dd = dr[k];
          if (dd) { const int l2 = (int)lvl[dd - 1] + 1; m = m > l2 ? m : l2; }
        }
        const bool ch = (m != lvprev);
        lvprev = m;
        lvl[i] = (unsigned short)m;
        if (!__any(ch)) break;
      }
    }
    // ---- backward transitive liveness: reverse groups ----
    for (int grp = 63; grp >= 0; --grp) {
      const int i = grp * 64 + t;
      const ushort8 dr = *(const ushort8*)&deps[i][0];
      for (;;) {
        bool ch = false;
        if (liv[i]) {
          #pragma unroll
          for (int k = 0; k < MD; ++k) {
            const int dd = dr[k];
            if (dd && !liv[dd - 1]) { liv[dd - 1] = 1; ch = true; }
          }
        }
        if (!__any(ch)) break;
      }
    }
  }
  __syncthreads();

  // ---- counting sort by key = 2*level + (dead?1:0) ----
  for (int i = t; i < NN; i += 1024) {
    const int lv = lvl[i];
    atomicAdd(&cnt[2 * lv + (liv[i] ? 0 : 1)], 1);
    atomicMax(&s_max, lv);
  }
  __syncthreads();
  const int nL = s_max + 1;
  if (t == 0) {
    int off = 0;
    for (int l = 0; l < nL; ++l) {
      meta[MI_LO + l] = off;
      meta[MI_NL + l] = cnt[2 * l];
      const int a = cnt[2 * l], b = cnt[2 * l + 1];
      cnt[2 * l] = off; off += a;
      cnt[2 * l + 1] = off; off += b;
    }
    meta[MI_LO + nL] = off;
    meta[MI_NLEV] = nL;
  }
  __syncthreads();
  for (int i = t; i < NN; i += 1024)
    pos[i] = atomicAdd(&cnt[2 * lvl[i] + (liv[i] ? 0 : 1)], 1);
  __syncthreads();
  for (int i = t; i < NN; i += 1024) {
    const int r = pos[i];
    meta[MI_PERM + r] = i;
    int nd = 0;
    #pragma unroll
    for (int k = 0; k < MD; ++k) {
      const int dd = deps[i][k];
      if (dd) { meta[MI_DPOS + r * MD + nd] = pos[dd - 1]; ++nd; }
    }
    for (int k = nd; k < MD; ++k) meta[MI_DPOS + r * MD + k] = 0;
    meta[MI_DCNT + r] = nd;
    ((float*)meta)[MI_INV + r] = nd ? 1.0f / (float)nd : 0.0f;
  }
  if (t == 0) meta[MI_ROOTPOS] = pos[NN - 1];
  for (int i = t; i < NW; i += 1024) meta[MI_ARRIVE + i] = 0;
}

// ---------------- preQ = Qb @ bf16(W1[:, :1024])^T + b1  (MFMA bf16) ----------------
__global__ __launch_bounds__(256) void k_preq(
    const unsigned short* __restrict__ Qb, const float* __restrict__ W1,
    const float* __restrict__ b1, float* __restrict__ preQ) {
  const int t = threadIdx.x;
  const int wave = t >> 6, lane = t & 63;
  const int wm = wave >> 1, wn = wave & 1;
  const int m0 = blockIdx.y * 128 + wm * 64;
  const int n0 = blockIdx.x * 128 + wn * 64;
  const int lrow = lane & 15;           // A/B row within 16
  const int klo = (lane >> 4) * 8;      // k sub-chunk
  f32x4 acc[4][4] = {};
  for (int k0 = 0; k0 < DM; k0 += 32) {
    bf16x8 af[4];
    #pragma unroll
    for (int f = 0; f < 4; ++f)
      af[f] = *(const bf16x8*)&Qb[(size_t)(m0 + f * 16 + lrow) * DM + k0 + klo];
    bf16x8 bfr[4];
    #pragma unroll
    for (int g = 0; g < 4; ++g) {
      const float* wsrc = &W1[(size_t)(n0 + g * 16 + lrow) * 2048 + k0 + klo];
      float4 w0 = *(const float4*)&wsrc[0];
      float4 w1 = *(const float4*)&wsrc[4];
      bf16x8 bb;
      bb[0] = (short)f2bf(w0.x); bb[1] = (short)f2bf(w0.y);
      bb[2] = (short)f2bf(w0.z); bb[3] = (short)f2bf(w0.w);
      bb[4] = (short)f2bf(w1.x); bb[5] = (short)f2bf(w1.y);
      bb[6] = (short)f2bf(w1.z); bb[7] = (short)f2bf(w1.w);
      bfr[g] = bb;
    }
    #pragma unroll
    for (int f = 0; f < 4; ++f)
      #pragma unroll
      for (int g = 0; g < 4; ++g)
        acc[f][g] = __builtin_amdgcn_mfma_f32_16x16x32_bf16(af[f], bfr[g], acc[f][g], 0, 0, 0);
  }
  float b1v[4];
  #pragma unroll
  for (int g = 0; g < 4; ++g) b1v[g] = b1[n0 + g * 16 + lrow];
  const int mrow = (lane >> 4) * 4;
  #pragma unroll
  for (int f = 0; f < 4; ++f)
    #pragma unroll
    for (int g = 0; g < 4; ++g) {
      const int n = n0 + g * 16 + lrow;
      #pragma unroll
      for (int r = 0; r < 4; ++r)
        preQ[(size_t)(m0 + f * 16 + mrow + r) * DM + n] = acc[f][g][r] + b1v[g];
    }
}

// ---------------- persistent column-sliced dataflow (bf16 h, W in VGPRs) + logits ----------------
__global__ __launch_bounds__(NT) void k_levels(
    const float* __restrict__ W1, const float* __restrict__ preQ,
    unsigned short* __restrict__ hPb, float4* __restrict__ gPan, int* __restrict__ meta,
    const float* __restrict__ W2, const float* __restrict__ b2, float* __restrict__ out) {
  const int tid = threadIdx.x;
  const int wb = blockIdx.x;
  const int c0 = wb * NCOL;
  const int wave = tid >> 6, lane = tid & 63;
  const int nL = meta[MI_NLEV];
  const int rootRow = meta[MI_ROOTPOS];
  __shared__ int s_lo[MAXL];
  __shared__ int s_nl[MAXL];
  __shared__ float4 preLDS[NT];
  for (int i = tid; i <= nL; i += NT) s_lo[i] = meta[MI_LO + i];
  for (int i = tid; i < nL; i += NT) s_nl[i] = meta[MI_NL + i];
  // W1c slice (4 cols x 1024 k) fp32 in registers; lane's k-window = lane*16..+15
  float4 wreg[NCOL][4];
  #pragma unroll
  for (int cc = 0; cc < NCOL; ++cc)
    #pragma unroll
    for (int q = 0; q < 4; ++q)
      wreg[cc][q] = *(const float4*)&W1[(size_t)(c0 + cc) * 2048 + 1024 + lane * 16 + q * 4];
  __syncthreads();
  float4* gp = gPan + (size_t)wb * NN;   // block-private g panel (fp32)
  const float* invA = (const float*)&meta[MI_INV];

  for (int l = 0; l < nL; ++l) {
    const int lo = s_lo[l];
    const int nA = s_nl[l];   // live rows (live-first ordering)

    // ---- A-phase: thread-per-row, own 4 columns; pack to bf16, 8B agent store ----
    for (int r = lo + tid; r < lo + nA; r += NT) {
      const int node = meta[MI_PERM + r];
      const int nd = meta[MI_DCNT + r];
      const float iv = invA[r];
      const int4 p0 = *(const int4*)&meta[MI_DPOS + r * MD];
      const int4 p1 = *(const int4*)&meta[MI_DPOS + r * MD + 4];
      const int dps[8] = {p0.x, p0.y, p0.z, p0.w, p1.x, p1.y, p1.z, p1.w};
      float sx = 0.f, sy = 0.f, sz = 0.f, sw = 0.f;
      #pragma unroll
      for (int d = 0; d < MD; ++d) {
        float4 v = gp[dps[d]];
        sx += (d < nd) ? v.x : 0.f;
        sy += (d < nd) ? v.y : 0.f;
        sz += (d < nd) ? v.z : 0.f;
        sw += (d < nd) ? v.w : 0.f;
      }
      const float4 pq = (l > 0 && r == lo + tid) ? preLDS[tid]
                                                 : *(const float4*)&preQ[(size_t)node * DM + c0];
      const unsigned short h0 = f2bf(gelu_f(pq.x + sx * iv));
      const unsigned short h1 = f2bf(gelu_f(pq.y + sy * iv));
      const unsigned short h2 = f2bf(gelu_f(pq.z + sz * iv));
      const unsigned short h3 = f2bf(gelu_f(pq.w + sw * iv));
      const unsigned long long u = (unsigned long long)h0 | ((unsigned long long)h1 << 16)
                                 | ((unsigned long long)h2 << 32) | ((unsigned long long)h3 << 48);
      __hip_atomic_store((unsigned long long*)&hPb[(size_t)r * DM + c0], u,
                         __ATOMIC_RELAXED, __HIP_MEMORY_SCOPE_AGENT);
    }
    __syncthreads();   // drains vmcnt before s_barrier -> h stores MALL-visible
    if (tid == 0)
      __hip_atomic_store(&meta[MI_ARRIVE + wb], l + 1, __ATOMIC_RELAXED, __HIP_MEMORY_SCOPE_AGENT);
    // prefetch next level's preQ into LDS while the barrier resolves
    if (l + 1 < nL && tid < s_nl[l + 1]) {
      const int node2 = meta[MI_PERM + s_lo[l + 1] + tid];
      preLDS[tid] = *(const float4*)&preQ[(size_t)node2 * DM + c0];
    }
    if (tid < 64) {
      for (;;) {
        int m = 1 << 30;
        #pragma unroll
        for (int u = 0; u < 4; ++u) {
          int v = __hip_atomic_load(&meta[MI_ARRIVE + tid * 4 + u], __ATOMIC_RELAXED, __HIP_MEMORY_SCOPE_AGENT);
          m = v < m ? v : m;
        }
        #pragma unroll
        for (int off = 1; off < 64; off <<= 1) {
          int o = __shfl_xor(m, off);
          m = o < m ? o : m;
        }
        if (m >= l + 1) break;
        __builtin_amdgcn_s_sleep(1);
      }
    }
    __syncthreads();

    // ---- B-phase: 4-row unrolled wave-per-row; h bf16, W from VGPRs ----
    for (int base = wave * UR; base < nA; base += NWAVE * UR) {
      const int cnt = nA - base;            // rows remaining (>=1)
      ushort8 hv[UR][2];
      #pragma unroll
      for (int u = 0; u < UR; ++u) {
        const int r = lo + base + ((u < cnt) ? u : 0);
        const ushort8* h8 = (const ushort8*)&hPb[(size_t)r * DM];
        hv[u][0] = h8[lane * 2];
        hv[u][1] = h8[lane * 2 + 1];
      }
      float rr[UR][NCOL];
      #pragma unroll
      for (int u = 0; u < UR; ++u) {
        float hf[16];
        #pragma unroll
        for (int e = 0; e < 8; ++e) { hf[e] = bf2f(hv[u][0][e]); hf[8 + e] = bf2f(hv[u][1][e]); }
        #pragma unroll
        for (int cc = 0; cc < NCOL; ++cc) {
          float a = 0.f;
          #pragma unroll
          for (int q = 0; q < 4; ++q)
            a += hf[q * 4 + 0] * wreg[cc][q].x + hf[q * 4 + 1] * wreg[cc][q].y
               + hf[q * 4 + 2] * wreg[cc][q].z + hf[q * 4 + 3] * wreg[cc][q].w;
          rr[u][cc] = a;
        }
      }
      #pragma unroll
      for (int off = 1; off < 64; off <<= 1)
        #pragma unroll
        for (int u = 0; u < UR; ++u)
          #pragma unroll
          for (int cc = 0; cc < NCOL; ++cc)
            rr[u][cc] += __shfl_xor(rr[u][cc], off);
      if (lane == 0) {
        #pragma unroll
        for (int u = 0; u < UR; ++u)
          if (u < cnt) gp[lo + base + u] = make_float4(rr[u][0], rr[u][1], rr[u][2], rr[u][3]);
      }
    }
    __syncthreads();   // own-panel writes visible block-wide for next level's A
  }

  // ---- logits epilogue (block 0): out = W2 @ h[root] + b2 ----
  if (wb == 0) {
    float* red = (float*)preLDS;
    const int j = tid >> 3, kc = tid & 7;   // 64 classes x 8 partials
    const ushort8* h8 = (const ushort8*)&hPb[(size_t)rootRow * DM];
    const float* wr2 = W2 + (size_t)j * DM;
    float acc = 0.f;
    for (int k = kc * 128; k < kc * 128 + 128; k += 8) {
      ushort8 hv = h8[k >> 3];
      float4 wa = *(const float4*)&wr2[k];
      float4 wb4 = *(const float4*)&wr2[k + 4];
      acc += bf2f(hv[0]) * wa.x + bf2f(hv[1]) * wa.y + bf2f(hv[2]) * wa.z + bf2f(hv[3]) * wa.w
           + bf2f(hv[4]) * wb4.x + bf2f(hv[5]) * wb4.y + bf2f(hv[6]) * wb4.z + bf2f(hv[7]) * wb4.w;
    }
    red[tid] = acc;
    __syncthreads();
    if (kc == 0) {
      float s = 0.f;
      #pragma unroll
      for (int e = 0; e < 8; ++e) s += red[j * 8 + e];
      out[j] = s + b2[j];
    }
  }
}

extern "C" void kernel_launch(void* const* d_in, const int* in_sizes, int n_in,
                              void* d_out, int out_size, void* d_ws, size_t ws_size,
                              hipStream_t stream) {
  const float* Q        = (const float*)d_in[0];
  const float* W1       = (const float*)d_in[1];
  const float* b1       = (const float*)d_in[2];
  const float* W2       = (const float*)d_in[3];
  const float* b2       = (const float*)d_in[4];
  const int*   dep_idx  = (const int*)d_in[5];
  const int*   dep_mask = (const int*)d_in[6];

  char* ws = (char*)d_ws;
  float*          preQ = (float*)ws;                              // [0, 16MB)
  unsigned short* hPb  = (unsigned short*)(ws + (16ull << 20));   // [16, 24) bf16 h
  unsigned short* Qb   = (unsigned short*)(ws + (24ull << 20));   // [24, 32) bf16 Q
  float4*         gPan = (float4*)(ws + (32ull << 20));           // [32, 48) block-private g
  int*            meta = (int*)(ws + (48ull << 20));
  float*          out  = (float*)d_out;

  k_pro<<<dim3(257), dim3(1024), 0, stream>>>(Q, dep_idx, dep_mask, meta, Qb);
  k_preq<<<dim3(DM / 128, NN / 128), dim3(256), 0, stream>>>(Qb, W1, b1, preQ);
  k_levels<<<dim3(NW), dim3(NT), 0, stream>>>(W1, preQ, hPb, gPan, meta, W2, b2, out);
}

// Round 9
// 536.008 us; speedup vs baseline: 17.1477x; 1.0380x over previous
//
#include <hip/hip_runtime.h>

#define NN 4096
#define DM 1024
#define MD 8
#define NW 256          // worker blocks = column slices
#define NCOL 4          // columns per block (NW*NCOL = DM)
#define NT 512          // threads per k_levels block
#define NWAVE (NT / 64)
#define UR 4            // B-phase row unroll per wave
#define MAXL 4097

// meta layout (int offsets within meta region of d_ws)
#define MI_NLEV 0
#define MI_ROOTPOS 1
#define MI_ARRIVE 8     // arrive[NW]
#define MI_LO 1024      // levelOffset[nL+1]
#define MI_NL 6144      // live count per level
#define MI_NU 10240     // urgent count per level
#define MI_PERM 14336   // perm[4096] (row -> node)
#define MI_DCNT 18432   // dep count per permuted row
#define MI_INV 22528    // (float) 1/nd per permuted row
#define MI_DPOS 26624   // dpos[4096*8]: permuted dep rows (padded with 0)

typedef __attribute__((ext_vector_type(8))) short bf16x8;
typedef __attribute__((ext_vector_type(8))) unsigned short ushort8;
typedef __attribute__((ext_vector_type(4))) float f32x4;

__device__ __forceinline__ float gelu_f(float x) {
  return 0.5f * x * (1.0f + erff(x * 0.70710678118654752440f));
}
__device__ __forceinline__ unsigned short f2bf(float x) {   // RTNE
  unsigned int u = __builtin_bit_cast(unsigned int, x);
  u += 0x7FFFu + ((u >> 16) & 1u);
  return (unsigned short)(u >> 16);
}
__device__ __forceinline__ float bf2f(unsigned short v) {
  return __builtin_bit_cast(float, (unsigned int)v << 16);
}

// ---------------- fused: block 0 = graph prologue (chunked Gauss-Seidel, 1024 thr);
// ---------------- blocks 1..255 = Q -> bf16 conversion (grid-stride) ----------------
__global__ __launch_bounds__(1024) void k_pro(
    const float* __restrict__ Q, const int* __restrict__ dep_idx,
    const int* __restrict__ dep_mask, int* __restrict__ meta,
    unsigned short* __restrict__ Qb) {
  __shared__ int lvl[NN];     // 16KB
  __shared__ int liv[NN];     // 16KB
  __shared__ int mcl[NN];     // 16KB (min consumer level; reused as sort key)
  __shared__ int cnt[3 * NN]; // 48KB
  __shared__ int pos[NN];     // 16KB   (112KB total)
  __shared__ int s_changed, s_max;
  const int t = threadIdx.x;

  if (blockIdx.x != 0) {
    // ---- cvtq: 8 floats/thread, grid-stride over 255 blocks ----
    const size_t total = (size_t)NN * DM / 8;
    for (size_t c = (size_t)(blockIdx.x - 1) * 1024 + t; c < total; c += 255 * 1024) {
      const size_t i = c * 8;
      float4 a = *(const float4*)&Q[i];
      float4 b = *(const float4*)&Q[i + 4];
      ushort8 o;
      o[0] = f2bf(a.x); o[1] = f2bf(a.y); o[2] = f2bf(a.z); o[3] = f2bf(a.w);
      o[4] = f2bf(b.x); o[5] = f2bf(b.y); o[6] = f2bf(b.z); o[7] = f2bf(b.w);
      *(ushort8*)&Qb[i] = o;
    }
    return;
  }

  for (int i = t; i < NN; i += 1024) {
    lvl[i] = 0; liv[i] = (i == NN - 1) ? 1 : 0; mcl[i] = 0x7FFFFFFF;
  }
  for (int i = t; i < 3 * NN; i += 1024) cnt[i] = 0;
  if (t == 0) s_max = 0;
  __syncthreads();

  // ---- forward longest-path levels: 4 chunks of 1024 in index order ----
  for (int u = 0; u < 4; ++u) {
    const int i = u * 1024 + t;
    const int4 d0 = *(const int4*)&dep_idx[i * MD];
    const int4 d1 = *(const int4*)&dep_idx[i * MD + 4];
    const int4 m0 = *(const int4*)&dep_mask[i * MD];
    const int4 m1 = *(const int4*)&dep_mask[i * MD + 4];
    int my = 0;
    for (;;) {
      if (t == 0) s_changed = 0;
      __syncthreads();
      int m = 0;
      if (m0.x) { int l = lvl[d0.x] + 1; m = m > l ? m : l; }
      if (m0.y) { int l = lvl[d0.y] + 1; m = m > l ? m : l; }
      if (m0.z) { int l = lvl[d0.z] + 1; m = m > l ? m : l; }
      if (m0.w) { int l = lvl[d0.w] + 1; m = m > l ? m : l; }
      if (m1.x) { int l = lvl[d1.x] + 1; m = m > l ? m : l; }
      if (m1.y) { int l = lvl[d1.y] + 1; m = m > l ? m : l; }
      if (m1.z) { int l = lvl[d1.z] + 1; m = m > l ? m : l; }
      if (m1.w) { int l = lvl[d1.w] + 1; m = m > l ? m : l; }
      if (m > my) { my = m; lvl[i] = m; s_changed = 1; }
      __syncthreads();
      if (!s_changed) break;
    }
  }
  // ---- backward transitive liveness from root (reverse chunks) ----
  for (int u = 3; u >= 0; --u) {
    const int i = u * 1024 + t;
    const int4 d0 = *(const int4*)&dep_idx[i * MD];
    const int4 d1 = *(const int4*)&dep_idx[i * MD + 4];
    const int4 m0 = *(const int4*)&dep_mask[i * MD];
    const int4 m1 = *(const int4*)&dep_mask[i * MD + 4];
    for (;;) {
      if (t == 0) s_changed = 0;
      __syncthreads();
      bool ch = false;
      if (liv[i]) {
        if (m0.x && !liv[d0.x]) { liv[d0.x] = 1; ch = true; }
        if (m0.y && !liv[d0.y]) { liv[d0.y] = 1; ch = true; }
        if (m0.z && !liv[d0.z]) { liv[d0.z] = 1; ch = true; }
        if (m0.w && !liv[d0.w]) { liv[d0.w] = 1; ch = true; }
        if (m1.x && !liv[d1.x]) { liv[d1.x] = 1; ch = true; }
        if (m1.y && !liv[d1.y]) { liv[d1.y] = 1; ch = true; }
        if (m1.z && !liv[d1.z]) { liv[d1.z] = 1; ch = true; }
        if (m1.w && !liv[d1.w]) { liv[d1.w] = 1; ch = true; }
      }
      if (ch) s_changed = 1;
      __syncthreads();
      if (!s_changed) break;
    }
  }
  // ---- min consumer level over live consumers ----
  for (int i = t; i < NN; i += 1024) {
    if (!liv[i]) continue;
    const int4 d0 = *(const int4*)&dep_idx[i * MD];
    const int4 d1 = *(const int4*)&dep_idx[i * MD + 4];
    const int4 m0 = *(const int4*)&dep_mask[i * MD];
    const int4 m1 = *(const int4*)&dep_mask[i * MD + 4];
    const int L = lvl[i];
    if (m0.x) atomicMin(&mcl[d0.x], L);
    if (m0.y) atomicMin(&mcl[d0.y], L);
    if (m0.z) atomicMin(&mcl[d0.z], L);
    if (m0.w) atomicMin(&mcl[d0.w], L);
    if (m1.x) atomicMin(&mcl[d1.x], L);
    if (m1.y) atomicMin(&mcl[d1.y], L);
    if (m1.z) atomicMin(&mcl[d1.z], L);
    if (m1.w) atomicMin(&mcl[d1.w], L);
  }
  __syncthreads();
  // ---- counting sort by key = 3*level + {0:urgent, 1:lazy, 2:dead} ----
  for (int i = t; i < NN; i += 1024) {
    const int key = liv[i] ? ((mcl[i] == lvl[i] + 1) ? 0 : 1) : 2;
    mcl[i] = key;
    atomicAdd(&cnt[3 * lvl[i] + key], 1);
    atomicMax(&s_max, lvl[i]);
  }
  __syncthreads();
  const int nL = s_max + 1;
  if (t == 0) {
    int off = 0;
    for (int l = 0; l < nL; ++l) {
      meta[MI_LO + l] = off;
      const int a = cnt[3 * l], b = cnt[3 * l + 1], c = cnt[3 * l + 2];
      meta[MI_NU + l] = a;
      meta[MI_NL + l] = a + b;
      cnt[3 * l] = off; off += a;
      cnt[3 * l + 1] = off; off += b;
      cnt[3 * l + 2] = off; off += c;
    }
    meta[MI_LO + nL] = off;
    meta[MI_NLEV] = nL;
  }
  __syncthreads();
  for (int i = t; i < NN; i += 1024)
    pos[i] = atomicAdd(&cnt[3 * lvl[i] + mcl[i]], 1);
  __syncthreads();
  for (int i = t; i < NN; i += 1024) {
    const int r = pos[i];
    meta[MI_PERM + r] = i;
    const int4 d0 = *(const int4*)&dep_idx[i * MD];
    const int4 d1 = *(const int4*)&dep_idx[i * MD + 4];
    const int4 m0 = *(const int4*)&dep_mask[i * MD];
    const int4 m1 = *(const int4*)&dep_mask[i * MD + 4];
    const int dd[8] = {d0.x, d0.y, d0.z, d0.w, d1.x, d1.y, d1.z, d1.w};
    const int mm[8] = {m0.x, m0.y, m0.z, m0.w, m1.x, m1.y, m1.z, m1.w};
    int nd = 0;
    #pragma unroll
    for (int k = 0; k < MD; ++k)
      if (mm[k]) { meta[MI_DPOS + r * MD + nd] = pos[dd[k]]; ++nd; }
    for (int k = nd; k < MD; ++k) meta[MI_DPOS + r * MD + k] = 0;
    meta[MI_DCNT + r] = nd;
    ((float*)meta)[MI_INV + r] = nd ? 1.0f / (float)nd : 0.0f;
  }
  if (t == 0) meta[MI_ROOTPOS] = pos[NN - 1];
  for (int i = t; i < NW; i += 1024) meta[MI_ARRIVE + i] = 0;
}

// ---------------- preQ = Qb @ bf16(W1[:, :1024])^T + b1  (MFMA bf16) ----------------
__global__ __launch_bounds__(256) void k_preq(
    const unsigned short* __restrict__ Qb, const float* __restrict__ W1,
    const float* __restrict__ b1, float* __restrict__ preQ) {
  const int t = threadIdx.x;
  const int wave = t >> 6, lane = t & 63;
  const int wm = wave >> 1, wn = wave & 1;
  const int m0 = blockIdx.y * 128 + wm * 64;
  const int n0 = blockIdx.x * 128 + wn * 64;
  const int lrow = lane & 15;           // A/B row within 16
  const int klo = (lane >> 4) * 8;      // k sub-chunk
  f32x4 acc[4][4] = {};
  for (int k0 = 0; k0 < DM; k0 += 32) {
    bf16x8 af[4];
    #pragma unroll
    for (int f = 0; f < 4; ++f)
      af[f] = *(const bf16x8*)&Qb[(size_t)(m0 + f * 16 + lrow) * DM + k0 + klo];
    bf16x8 bfr[4];
    #pragma unroll
    for (int g = 0; g < 4; ++g) {
      const float* wsrc = &W1[(size_t)(n0 + g * 16 + lrow) * 2048 + k0 + klo];
      float4 w0 = *(const float4*)&wsrc[0];
      float4 w1 = *(const float4*)&wsrc[4];
      bf16x8 bb;
      bb[0] = (short)f2bf(w0.x); bb[1] = (short)f2bf(w0.y);
      bb[2] = (short)f2bf(w0.z); bb[3] = (short)f2bf(w0.w);
      bb[4] = (short)f2bf(w1.x); bb[5] = (short)f2bf(w1.y);
      bb[6] = (short)f2bf(w1.z); bb[7] = (short)f2bf(w1.w);
      bfr[g] = bb;
    }
    #pragma unroll
    for (int f = 0; f < 4; ++f)
      #pragma unroll
      for (int g = 0; g < 4; ++g)
        acc[f][g] = __builtin_amdgcn_mfma_f32_16x16x32_bf16(af[f], bfr[g], acc[f][g], 0, 0, 0);
  }
  float b1v[4];
  #pragma unroll
  for (int g = 0; g < 4; ++g) b1v[g] = b1[n0 + g * 16 + lrow];
  const int mrow = (lane >> 4) * 4;
  #pragma unroll
  for (int f = 0; f < 4; ++f)
    #pragma unroll
    for (int g = 0; g < 4; ++g) {
      const int n = n0 + g * 16 + lrow;
      #pragma unroll
      for (int r = 0; r < 4; ++r)
        preQ[(size_t)(m0 + f * 16 + mrow + r) * DM + n] = acc[f][g][r] + b1v[g];
    }
}

// ---------------- persistent column-sliced dataflow (bf16 h, W in VGPRs,
// ---------------- urgent/lazy B split) + logits epilogue ----------------
__global__ __launch_bounds__(NT) void k_levels(
    const float* __restrict__ W1, const float* __restrict__ preQ,
    unsigned short* __restrict__ hPb, float4* __restrict__ gPan, int* __restrict__ meta,
    const float* __restrict__ W2, const float* __restrict__ b2, float* __restrict__ out) {
  const int tid = threadIdx.x;
  const int wb = blockIdx.x;
  const int c0 = wb * NCOL;
  const int wave = tid >> 6, lane = tid & 63;
  const int nL = meta[MI_NLEV];
  const int rootRow = meta[MI_ROOTPOS];
  __shared__ int s_lo[MAXL];
  __shared__ int s_nl[MAXL];
  __shared__ int s_nu[MAXL];
  __shared__ float4 preLDS[NT];
  for (int i = tid; i <= nL; i += NT) s_lo[i] = meta[MI_LO + i];
  for (int i = tid; i < nL; i += NT) { s_nl[i] = meta[MI_NL + i]; s_nu[i] = meta[MI_NU + i]; }
  // W1c slice (4 cols x 1024 k) fp32 in registers; lane's k-window = lane*16..+15
  float4 wreg[NCOL][4];
  #pragma unroll
  for (int cc = 0; cc < NCOL; ++cc)
    #pragma unroll
    for (int q = 0; q < 4; ++q)
      wreg[cc][q] = *(const float4*)&W1[(size_t)(c0 + cc) * 2048 + 1024 + lane * 16 + q * 4];
  __syncthreads();
  float4* gp = gPan + (size_t)wb * NN;   // block-private g panel (fp32)
  const float* invA = (const float*)&meta[MI_INV];

  // B-GEMV over absolute row range [rlo, rhi)
  auto bphase = [&](int rlo, int rhi) {
    for (int base = rlo + wave * UR; base < rhi; base += NWAVE * UR) {
      const int cnt = rhi - base;          // rows remaining (>=1)
      ushort8 hv[UR][2];
      #pragma unroll
      for (int u = 0; u < UR; ++u) {
        const int r = base + ((u < cnt) ? u : 0);
        const ushort8* h8 = (const ushort8*)&hPb[(size_t)r * DM];
        hv[u][0] = h8[lane * 2];
        hv[u][1] = h8[lane * 2 + 1];
      }
      float rr[UR][NCOL];
      #pragma unroll
      for (int u = 0; u < UR; ++u) {
        float hf[16];
        #pragma unroll
        for (int e = 0; e < 8; ++e) { hf[e] = bf2f(hv[u][0][e]); hf[8 + e] = bf2f(hv[u][1][e]); }
        #pragma unroll
        for (int cc = 0; cc < NCOL; ++cc) {
          float a = 0.f;
          #pragma unroll
          for (int q = 0; q < 4; ++q)
            a += hf[q * 4 + 0] * wreg[cc][q].x + hf[q * 4 + 1] * wreg[cc][q].y
               + hf[q * 4 + 2] * wreg[cc][q].z + hf[q * 4 + 3] * wreg[cc][q].w;
          rr[u][cc] = a;
        }
      }
      #pragma unroll
      for (int off = 1; off < 64; off <<= 1)
        #pragma unroll
        for (int u = 0; u < UR; ++u)
          #pragma unroll
          for (int cc = 0; cc < NCOL; ++cc)
            rr[u][cc] += __shfl_xor(rr[u][cc], off);
      if (lane == 0) {
        #pragma unroll
        for (int u = 0; u < UR; ++u)
          if (u < cnt) gp[base + u] = make_float4(rr[u][0], rr[u][1], rr[u][2], rr[u][3]);
      }
    }
  };

  int plo = 0, pnu = 0, pnl = 0;   // previous level's lazy range
  for (int l = 0; l < nL; ++l) {
    const int lo = s_lo[l];
    const int nl = s_nl[l];   // live rows (urgent-first ordering)
    const int nu = s_nu[l];   // urgent rows

    // ---- A-phase: thread-per-row, own 4 columns; pack to bf16, 8B agent store ----
    for (int r = lo + tid; r < lo + nl; r += NT) {
      const int node = meta[MI_PERM + r];
      const int nd = meta[MI_DCNT + r];
      const float iv = invA[r];
      const int4 p0 = *(const int4*)&meta[MI_DPOS + r * MD];
      const int4 p1 = *(const int4*)&meta[MI_DPOS + r * MD + 4];
      const int dps[8] = {p0.x, p0.y, p0.z, p0.w, p1.x, p1.y, p1.z, p1.w};
      float sx = 0.f, sy = 0.f, sz = 0.f, sw = 0.f;
      #pragma unroll
      for (int d = 0; d < MD; ++d) {
        float4 v = gp[dps[d]];
        sx += (d < nd) ? v.x : 0.f;
        sy += (d < nd) ? v.y : 0.f;
        sz += (d < nd) ? v.z : 0.f;
        sw += (d < nd) ? v.w : 0.f;
      }
      const float4 pq = (l > 0 && r == lo + tid) ? preLDS[tid]
                                                 : *(const float4*)&preQ[(size_t)node * DM + c0];
      const unsigned short h0 = f2bf(gelu_f(pq.x + sx * iv));
      const unsigned short h1 = f2bf(gelu_f(pq.y + sy * iv));
      const unsigned short h2 = f2bf(gelu_f(pq.z + sz * iv));
      const unsigned short h3 = f2bf(gelu_f(pq.w + sw * iv));
      const unsigned long long u = (unsigned long long)h0 | ((unsigned long long)h1 << 16)
                                 | ((unsigned long long)h2 << 32) | ((unsigned long long)h3 << 48);
      __hip_atomic_store((unsigned long long*)&hPb[(size_t)r * DM + c0], u,
                         __ATOMIC_RELAXED, __HIP_MEMORY_SCOPE_AGENT);
    }
    __syncthreads();   // drains vmcnt -> h stores MALL-visible
    if (tid == 0)
      __hip_atomic_store(&meta[MI_ARRIVE + wb], l + 1, __ATOMIC_RELAXED, __HIP_MEMORY_SCOPE_AGENT);
    // prefetch next level's preQ into LDS (overlaps barrier)
    if (l + 1 < nL && tid < s_nl[l + 1]) {
      const int node2 = meta[MI_PERM + s_lo[l + 1] + tid];
      preLDS[tid] = *(const float4*)&preQ[(size_t)node2 * DM + c0];
    }
    // ---- B2 of previous level (lazy rows): hidden inside the barrier window ----
    bphase(plo + pnu, plo + pnl);
    // ---- poll: all blocks' h(l) complete ----
    if (tid < 64) {
      for (;;) {
        int m = 1 << 30;
        #pragma unroll
        for (int u = 0; u < 4; ++u) {
          int v = __hip_atomic_load(&meta[MI_ARRIVE + tid * 4 + u], __ATOMIC_RELAXED, __HIP_MEMORY_SCOPE_AGENT);
          m = v < m ? v : m;
        }
        #pragma unroll
        for (int off = 1; off < 64; off <<= 1) {
          int o = __shfl_xor(m, off);
          m = o < m ? o : m;
        }
        if (m >= l + 1) break;
        __builtin_amdgcn_s_sleep(1);
      }
    }
    __syncthreads();
    // ---- B1: urgent rows of level l (feed A(l+1)) ----
    bphase(lo, lo + nu);
    plo = lo; pnu = nu; pnl = nl;
    __syncthreads();   // B1 g writes visible block-wide for next level's A
  }

  // ---- logits epilogue (block 0): out = W2 @ h[root] + b2 ----
  if (wb == 0) {
    float* red = (float*)preLDS;
    const int j = tid >> 3, kc = tid & 7;   // 64 classes x 8 partials
    const ushort8* h8 = (const ushort8*)&hPb[(size_t)rootRow * DM];
    const float* wr2 = W2 + (size_t)j * DM;
    float acc = 0.f;
    for (int k = kc * 128; k < kc * 128 + 128; k += 8) {
      ushort8 hv = h8[k >> 3];
      float4 wa = *(const float4*)&wr2[k];
      float4 wb4 = *(const float4*)&wr2[k + 4];
      acc += bf2f(hv[0]) * wa.x + bf2f(hv[1]) * wa.y + bf2f(hv[2]) * wa.z + bf2f(hv[3]) * wa.w
           + bf2f(hv[4]) * wb4.x + bf2f(hv[5]) * wb4.y + bf2f(hv[6]) * wb4.z + bf2f(hv[7]) * wb4.w;
    }
    red[tid] = acc;
    __syncthreads();
    if (kc == 0) {
      float s = 0.f;
      #pragma unroll
      for (int e = 0; e < 8; ++e) s += red[j * 8 + e];
      out[j] = s + b2[j];
    }
  }
}

extern "C" void kernel_launch(void* const* d_in, const int* in_sizes, int n_in,
                              void* d_out, int out_size, void* d_ws, size_t ws_size,
                              hipStream_t stream) {
  const float* Q        = (const float*)d_in[0];
  const float* W1       = (const float*)d_in[1];
  const float* b1       = (const float*)d_in[2];
  const float* W2       = (const float*)d_in[3];
  const float* b2       = (const float*)d_in[4];
  const int*   dep_idx  = (const int*)d_in[5];
  const int*   dep_mask = (const int*)d_in[6];

  char* ws = (char*)d_ws;
  float*          preQ = (float*)ws;                              // [0, 16MB)
  unsigned short* hPb  = (unsigned short*)(ws + (16ull << 20));   // [16, 24) bf16 h
  unsigned short* Qb   = (unsigned short*)(ws + (24ull << 20));   // [24, 32) bf16 Q
  float4*         gPan = (float4*)(ws + (32ull << 20));           // [32, 48) block-private g
  int*            meta = (int*)(ws + (48ull << 20));
  float*          out  = (float*)d_out;

  k_pro<<<dim3(256), dim3(1024), 0, stream>>>(Q, dep_idx, dep_mask, meta, Qb);
  k_preq<<<dim3(DM / 128, NN / 128), dim3(256), 0, stream>>>(Qb, W1, b1, preQ);
  k_levels<<<dim3(NW), dim3(NT), 0, stream>>>(W1, preQ, hPb, gPan, meta, W2, b2, out);
}

// Round 11
// 487.779 us; speedup vs baseline: 18.8431x; 1.0989x over previous
//
#include <hip/hip_runtime.h>

#define NN 4096
#define DM 1024
#define MD 8
#define NW 256          // worker blocks = column slices
#define NCOL 4          // columns per block (NW*NCOL = DM)
#define NT 512          // threads per k_levels block
#define NWAVE (NT / 64)
#define UR 4            // B-phase row unroll per wave
#define MAXL 4097

// meta layout (int offsets within meta region of d_ws) — R8 layout
#define MI_NLEV 0
#define MI_ROOTPOS 1
#define MI_ARRIVE 8     // arrive[NW]
#define MI_LO 1024      // levelOffset[nL+1]
#define MI_NL 6144      // live count per level
#define MI_PERM 10240   // perm[4096] (row -> node)
#define MI_DCNT 14336   // dep count per permuted row
#define MI_INV 18432    // (float) 1/nd per permuted row
#define MI_DPOS 22528   // dpos[4096*8]: permuted dep rows (padded with 0)

typedef __attribute__((ext_vector_type(8))) short bf16x8;
typedef __attribute__((ext_vector_type(8))) unsigned short ushort8;
typedef __attribute__((ext_vector_type(4))) float f32x4;

__device__ __forceinline__ float gelu_f(float x) {
  return 0.5f * x * (1.0f + erff(x * 0.70710678118654752440f));
}
__device__ __forceinline__ unsigned short f2bf(float x) {   // RTNE
  unsigned int u = __builtin_bit_cast(unsigned int, x);
  u += 0x7FFFu + ((u >> 16) & 1u);
  return (unsigned short)(u >> 16);
}
__device__ __forceinline__ float bf2f(unsigned short v) {
  return __builtin_bit_cast(float, (unsigned int)v << 16);
}

// ---------------- fused: block 0 = graph prologue (chunked Gauss-Seidel, 1024 thr);
// ---------------- blocks 1..255 = Q -> bf16 conversion (grid-stride) ----------------
__global__ __launch_bounds__(1024) void k_pro(
    const float* __restrict__ Q, const int* __restrict__ dep_idx,
    const int* __restrict__ dep_mask, int* __restrict__ meta,
    unsigned short* __restrict__ Qb) {
  __shared__ int lvl[NN];     // 16KB
  __shared__ int liv[NN];     // 16KB
  __shared__ int cnt[2 * NN]; // 32KB
  __shared__ int pos[NN];     // 16KB
  __shared__ int s_changed, s_max;
  const int t = threadIdx.x;

  if (blockIdx.x != 0) {
    // ---- cvtq: 8 floats/thread, grid-stride over 255 blocks ----
    const size_t total = (size_t)NN * DM / 8;
    for (size_t c = (size_t)(blockIdx.x - 1) * 1024 + t; c < total; c += 255 * 1024) {
      const size_t i = c * 8;
      float4 a = *(const float4*)&Q[i];
      float4 b = *(const float4*)&Q[i + 4];
      ushort8 o;
      o[0] = f2bf(a.x); o[1] = f2bf(a.y); o[2] = f2bf(a.z); o[3] = f2bf(a.w);
      o[4] = f2bf(b.x); o[5] = f2bf(b.y); o[6] = f2bf(b.z); o[7] = f2bf(b.w);
      *(ushort8*)&Qb[i] = o;
    }
    return;
  }

  for (int i = t; i < NN; i += 1024) { lvl[i] = 0; liv[i] = (i == NN - 1) ? 1 : 0; }
  for (int i = t; i < 2 * NN; i += 1024) cnt[i] = 0;
  if (t == 0) s_max = 0;
  __syncthreads();

  // ---- forward longest-path levels: 4 chunks of 1024 in index order ----
  for (int u = 0; u < 4; ++u) {
    const int i = u * 1024 + t;
    const int4 d0 = *(const int4*)&dep_idx[i * MD];
    const int4 d1 = *(const int4*)&dep_idx[i * MD + 4];
    const int4 m0 = *(const int4*)&dep_mask[i * MD];
    const int4 m1 = *(const int4*)&dep_mask[i * MD + 4];
    int my = 0;
    for (;;) {
      if (t == 0) s_changed = 0;
      __syncthreads();
      int m = 0;
      if (m0.x) { int l = lvl[d0.x] + 1; m = m > l ? m : l; }
      if (m0.y) { int l = lvl[d0.y] + 1; m = m > l ? m : l; }
      if (m0.z) { int l = lvl[d0.z] + 1; m = m > l ? m : l; }
      if (m0.w) { int l = lvl[d0.w] + 1; m = m > l ? m : l; }
      if (m1.x) { int l = lvl[d1.x] + 1; m = m > l ? m : l; }
      if (m1.y) { int l = lvl[d1.y] + 1; m = m > l ? m : l; }
      if (m1.z) { int l = lvl[d1.z] + 1; m = m > l ? m : l; }
      if (m1.w) { int l = lvl[d1.w] + 1; m = m > l ? m : l; }
      if (m > my) { my = m; lvl[i] = m; s_changed = 1; }
      __syncthreads();
      if (!s_changed) break;
    }
  }
  // ---- backward transitive liveness from root (reverse chunks) ----
  for (int u = 3; u >= 0; --u) {
    const int i = u * 1024 + t;
    const int4 d0 = *(const int4*)&dep_idx[i * MD];
    const int4 d1 = *(const int4*)&dep_idx[i * MD + 4];
    const int4 m0 = *(const int4*)&dep_mask[i * MD];
    const int4 m1 = *(const int4*)&dep_mask[i * MD + 4];
    for (;;) {
      if (t == 0) s_changed = 0;
      __syncthreads();
      bool ch = false;
      if (liv[i]) {
        if (m0.x && !liv[d0.x]) { liv[d0.x] = 1; ch = true; }
        if (m0.y && !liv[d0.y]) { liv[d0.y] = 1; ch = true; }
        if (m0.z && !liv[d0.z]) { liv[d0.z] = 1; ch = true; }
        if (m0.w && !liv[d0.w]) { liv[d0.w] = 1; ch = true; }
        if (m1.x && !liv[d1.x]) { liv[d1.x] = 1; ch = true; }
        if (m1.y && !liv[d1.y]) { liv[d1.y] = 1; ch = true; }
        if (m1.z && !liv[d1.z]) { liv[d1.z] = 1; ch = true; }
        if (m1.w && !liv[d1.w]) { liv[d1.w] = 1; ch = true; }
      }
      if (ch) s_changed = 1;
      __syncthreads();
      if (!s_changed) break;
    }
  }
  // ---- counting sort by key = 2*level + (dead?1:0) ----
  for (int i = t; i < NN; i += 1024) {
    atomicAdd(&cnt[2 * lvl[i] + (liv[i] ? 0 : 1)], 1);
    atomicMax(&s_max, lvl[i]);
  }
  __syncthreads();
  const int nL = s_max + 1;
  if (t == 0) {
    int off = 0;
    for (int l = 0; l < nL; ++l) {
      meta[MI_LO + l] = off;
      meta[MI_NL + l] = cnt[2 * l];
      const int a = cnt[2 * l], b = cnt[2 * l + 1];
      cnt[2 * l] = off; off += a;
      cnt[2 * l + 1] = off; off += b;
    }
    meta[MI_LO + nL] = off;
    meta[MI_NLEV] = nL;
  }
  __syncthreads();
  for (int i = t; i < NN; i += 1024)
    pos[i] = atomicAdd(&cnt[2 * lvl[i] + (liv[i] ? 0 : 1)], 1);
  __syncthreads();
  for (int i = t; i < NN; i += 1024) {
    const int r = pos[i];
    meta[MI_PERM + r] = i;
    const int4 d0 = *(const int4*)&dep_idx[i * MD];
    const int4 d1 = *(const int4*)&dep_idx[i * MD + 4];
    const int4 m0 = *(const int4*)&dep_mask[i * MD];
    const int4 m1 = *(const int4*)&dep_mask[i * MD + 4];
    const int dd[8] = {d0.x, d0.y, d0.z, d0.w, d1.x, d1.y, d1.z, d1.w};
    const int mm[8] = {m0.x, m0.y, m0.z, m0.w, m1.x, m1.y, m1.z, m1.w};
    int nd = 0;
    #pragma unroll
    for (int k = 0; k < MD; ++k)
      if (mm[k]) { meta[MI_DPOS + r * MD + nd] = pos[dd[k]]; ++nd; }
    for (int k = nd; k < MD; ++k) meta[MI_DPOS + r * MD + k] = 0;
    meta[MI_DCNT + r] = nd;
    ((float*)meta)[MI_INV + r] = nd ? 1.0f / (float)nd : 0.0f;
  }
  if (t == 0) meta[MI_ROOTPOS] = pos[NN - 1];
  for (int i = t; i < NW; i += 1024) meta[MI_ARRIVE + i] = 0;
}

// ---------------- preQ = Qb @ bf16(W1[:, :1024])^T + b1  (MFMA bf16) ----------------
__global__ __launch_bounds__(256) void k_preq(
    const unsigned short* __restrict__ Qb, const float* __restrict__ W1,
    const float* __restrict__ b1, float* __restrict__ preQ) {
  const int t = threadIdx.x;
  const int wave = t >> 6, lane = t & 63;
  const int wm = wave >> 1, wn = wave & 1;
  const int m0 = blockIdx.y * 128 + wm * 64;
  const int n0 = blockIdx.x * 128 + wn * 64;
  const int lrow = lane & 15;           // A/B row within 16
  const int klo = (lane >> 4) * 8;      // k sub-chunk
  f32x4 acc[4][4] = {};
  for (int k0 = 0; k0 < DM; k0 += 32) {
    bf16x8 af[4];
    #pragma unroll
    for (int f = 0; f < 4; ++f)
      af[f] = *(const bf16x8*)&Qb[(size_t)(m0 + f * 16 + lrow) * DM + k0 + klo];
    bf16x8 bfr[4];
    #pragma unroll
    for (int g = 0; g < 4; ++g) {
      const float* wsrc = &W1[(size_t)(n0 + g * 16 + lrow) * 2048 + k0 + klo];
      float4 w0 = *(const float4*)&wsrc[0];
      float4 w1 = *(const float4*)&wsrc[4];
      bf16x8 bb;
      bb[0] = (short)f2bf(w0.x); bb[1] = (short)f2bf(w0.y);
      bb[2] = (short)f2bf(w0.z); bb[3] = (short)f2bf(w0.w);
      bb[4] = (short)f2bf(w1.x); bb[5] = (short)f2bf(w1.y);
      bb[6] = (short)f2bf(w1.z); bb[7] = (short)f2bf(w1.w);
      bfr[g] = bb;
    }
    #pragma unroll
    for (int f = 0; f < 4; ++f)
      #pragma unroll
      for (int g = 0; g < 4; ++g)
        acc[f][g] = __builtin_amdgcn_mfma_f32_16x16x32_bf16(af[f], bfr[g], acc[f][g], 0, 0, 0);
  }
  float b1v[4];
  #pragma unroll
  for (int g = 0; g < 4; ++g) b1v[g] = b1[n0 + g * 16 + lrow];
  const int mrow = (lane >> 4) * 4;
  #pragma unroll
  for (int f = 0; f < 4; ++f)
    #pragma unroll
    for (int g = 0; g < 4; ++g) {
      const int n = n0 + g * 16 + lrow;
      #pragma unroll
      for (int r = 0; r < 4; ++r)
        preQ[(size_t)(m0 + f * 16 + mrow + r) * DM + n] = acc[f][g][r] + b1v[g];
    }
}

// ---------------- persistent column-sliced dataflow (bf16 h, W in VGPRs) + logits ----------------
__global__ __launch_bounds__(NT) void k_levels(
    const float* __restrict__ W1, const float* __restrict__ preQ,
    unsigned short* __restrict__ hPb, float4* __restrict__ gPan, int* __restrict__ meta,
    const float* __restrict__ W2, const float* __restrict__ b2, float* __restrict__ out) {
  const int tid = threadIdx.x;
  const int wb = blockIdx.x;
  const int c0 = wb * NCOL;
  const int wave = tid >> 6, lane = tid & 63;
  const int nL = meta[MI_NLEV];
  const int rootRow = meta[MI_ROOTPOS];
  __shared__ int s_lo[MAXL];
  __shared__ int s_nl[MAXL];
  __shared__ float4 preLDS[NT];
  for (int i = tid; i <= nL; i += NT) s_lo[i] = meta[MI_LO + i];
  for (int i = tid; i < nL; i += NT) s_nl[i] = meta[MI_NL + i];
  // W1c slice (4 cols x 1024 k) fp32 in registers; lane's k-window = lane*16..+15
  float4 wreg[NCOL][4];
  #pragma unroll
  for (int cc = 0; cc < NCOL; ++cc)
    #pragma unroll
    for (int q = 0; q < 4; ++q)
      wreg[cc][q] = *(const float4*)&W1[(size_t)(c0 + cc) * 2048 + 1024 + lane * 16 + q * 4];
  __syncthreads();
  float4* gp = gPan + (size_t)wb * NN;   // block-private g panel (fp32)
  const float* invA = (const float*)&meta[MI_INV];

  for (int l = 0; l < nL; ++l) {
    const int lo = s_lo[l];
    const int nA = s_nl[l];   // live rows (live-first ordering)

    // ---- A-phase: thread-per-row, own 4 columns; pack to bf16, 8B agent store ----
    for (int r = lo + tid; r < lo + nA; r += NT) {
      const int node = meta[MI_PERM + r];
      const int nd = meta[MI_DCNT + r];
      const float iv = invA[r];
      const int4 p0 = *(const int4*)&meta[MI_DPOS + r * MD];
      const int4 p1 = *(const int4*)&meta[MI_DPOS + r * MD + 4];
      const int dps[8] = {p0.x, p0.y, p0.z, p0.w, p1.x, p1.y, p1.z, p1.w};
      float sx = 0.f, sy = 0.f, sz = 0.f, sw = 0.f;
      #pragma unroll
      for (int d = 0; d < MD; ++d) {
        float4 v = gp[dps[d]];
        sx += (d < nd) ? v.x : 0.f;
        sy += (d < nd) ? v.y : 0.f;
        sz += (d < nd) ? v.z : 0.f;
        sw += (d < nd) ? v.w : 0.f;
      }
      const float4 pq = (l > 0 && r == lo + tid) ? preLDS[tid]
                                                 : *(const float4*)&preQ[(size_t)node * DM + c0];
      const unsigned short h0 = f2bf(gelu_f(pq.x + sx * iv));
      const unsigned short h1 = f2bf(gelu_f(pq.y + sy * iv));
      const unsigned short h2 = f2bf(gelu_f(pq.z + sz * iv));
      const unsigned short h3 = f2bf(gelu_f(pq.w + sw * iv));
      const unsigned long long u = (unsigned long long)h0 | ((unsigned long long)h1 << 16)
                                 | ((unsigned long long)h2 << 32) | ((unsigned long long)h3 << 48);
      __hip_atomic_store((unsigned long long*)&hPb[(size_t)r * DM + c0], u,
                         __ATOMIC_RELAXED, __HIP_MEMORY_SCOPE_AGENT);
    }
    __syncthreads();   // drains vmcnt -> h stores MALL-visible
    if (tid == 0)
      __hip_atomic_store(&meta[MI_ARRIVE + wb], l + 1, __ATOMIC_RELAXED, __HIP_MEMORY_SCOPE_AGENT);
    // prefetch next level's preQ into LDS (overlaps barrier)
    if (l + 1 < nL && tid < s_nl[l + 1]) {
      const int node2 = meta[MI_PERM + s_lo[l + 1] + tid];
      preLDS[tid] = *(const float4*)&preQ[(size_t)node2 * DM + c0];
    }
    if (tid < 64) {
      for (;;) {
        int m = 1 << 30;
        #pragma unroll
        for (int u = 0; u < 4; ++u) {
          int v = __hip_atomic_load(&meta[MI_ARRIVE + tid * 4 + u], __ATOMIC_RELAXED, __HIP_MEMORY_SCOPE_AGENT);
          m = v < m ? v : m;
        }
        #pragma unroll
        for (int off = 1; off < 64; off <<= 1) {
          int o = __shfl_xor(m, off);
          m = o < m ? o : m;
        }
        if (m >= l + 1) break;
        __builtin_amdgcn_s_sleep(1);
      }
    }
    __syncthreads();

    // ---- B-phase: 4-row unrolled wave-per-row; h bf16, W from VGPRs ----
    for (int base = wave * UR; base < nA; base += NWAVE * UR) {
      const int cnt = nA - base;            // rows remaining (>=1)
      ushort8 hv[UR][2];
      #pragma unroll
      for (int u = 0; u < UR; ++u) {
        const int r = lo + base + ((u < cnt) ? u : 0);
        const ushort8* h8 = (const ushort8*)&hPb[(size_t)r * DM];
        hv[u][0] = h8[lane * 2];
        hv[u][1] = h8[lane * 2 + 1];
      }
      float rr[UR][NCOL];
      #pragma unroll
      for (int u = 0; u < UR; ++u) {
        float hf[16];
        #pragma unroll
        for (int e = 0; e < 8; ++e) { hf[e] = bf2f(hv[u][0][e]); hf[8 + e] = bf2f(hv[u][1][e]); }
        #pragma unroll
        for (int cc = 0; cc < NCOL; ++cc) {
          float a = 0.f;
          #pragma unroll
          for (int q = 0; q < 4; ++q)
            a += hf[q * 4 + 0] * wreg[cc][q].x + hf[q * 4 + 1] * wreg[cc][q].y
               + hf[q * 4 + 2] * wreg[cc][q].z + hf[q * 4 + 3] * wreg[cc][q].w;
          rr[u][cc] = a;
        }
      }
      #pragma unroll
      for (int off = 1; off < 64; off <<= 1)
        #pragma unroll
        for (int u = 0; u < UR; ++u)
          #pragma unroll
          for (int cc = 0; cc < NCOL; ++cc)
            rr[u][cc] += __shfl_xor(rr[u][cc], off);
      if (lane == 0) {
        #pragma unroll
        for (int u = 0; u < UR; ++u)
          if (u < cnt) gp[lo + base + u] = make_float4(rr[u][0], rr[u][1], rr[u][2], rr[u][3]);
      }
    }
    __syncthreads();   // g writes visible block-wide for next level's A
  }

  // ---- logits epilogue (block 0): out = W2 @ h[root] + b2 ----
  if (wb == 0) {
    float* red = (float*)preLDS;
    const int j = tid >> 3, kc = tid & 7;   // 64 classes x 8 partials
    const ushort8* h8 = (const ushort8*)&hPb[(size_t)rootRow * DM];
    const float* wr2 = W2 + (size_t)j * DM;
    float acc = 0.f;
    for (int k = kc * 128; k < kc * 128 + 128; k += 8) {
      ushort8 hv = h8[k >> 3];
      float4 wa = *(const float4*)&wr2[k];
      float4 wb4 = *(const float4*)&wr2[k + 4];
      acc += bf2f(hv[0]) * wa.x + bf2f(hv[1]) * wa.y + bf2f(hv[2]) * wa.z + bf2f(hv[3]) * wa.w
           + bf2f(hv[4]) * wb4.x + bf2f(hv[5]) * wb4.y + bf2f(hv[6]) * wb4.z + bf2f(hv[7]) * wb4.w;
    }
    red[tid] = acc;
    __syncthreads();
    if (kc == 0) {
      float s = 0.f;
      #pragma unroll
      for (int e = 0; e < 8; ++e) s += red[j * 8 + e];
      out[j] = s + b2[j];
    }
  }
}

extern "C" void kernel_launch(void* const* d_in, const int* in_sizes, int n_in,
                              void* d_out, int out_size, void* d_ws, size_t ws_size,
                              hipStream_t stream) {
  const float* Q        = (const float*)d_in[0];
  const float* W1       = (const float*)d_in[1];
  const float* b1       = (const float*)d_in[2];
  const float* W2       = (const float*)d_in[3];
  const float* b2       = (const float*)d_in[4];
  const int*   dep_idx  = (const int*)d_in[5];
  const int*   dep_mask = (const int*)d_in[6];

  char* ws = (char*)d_ws;
  float*          preQ = (float*)ws;                              // [0, 16MB)
  unsigned short* hPb  = (unsigned short*)(ws + (16ull << 20));   // [16, 24) bf16 h
  unsigned short* Qb   = (unsigned short*)(ws + (24ull << 20));   // [24, 32) bf16 Q
  float4*         gPan = (float4*)(ws + (32ull << 20));           // [32, 48) block-private g
  int*            meta = (int*)(ws + (48ull << 20));
  float*          out  = (float*)d_out;

  k_pro<<<dim3(256), dim3(1024), 0, stream>>>(Q, dep_idx, dep_mask, meta, Qb);
  k_preq<<<dim3(DM / 128, NN / 128), dim3(256), 0, stream>>>(Qb, W1, b1, preQ);
  k_levels<<<dim3(NW), dim3(NT), 0, stream>>>(W1, preQ, hPb, gPan, meta, W2, b2, out);
}